// Round 10
// baseline (1049.661 us; speedup 1.0000x reference)
//
#include <hip/hip_runtime.h>

#define B_    16
#define CIN   100
#define T_    1024
#define CH_   512
#define HCH_  1536
#define NL_   8
#define NFFT_ 1024
#define HOP_  256
#define BT    (B_ * T_)
#define L_    1027
#define OROWS 1032   // padded o1 rows per batch: [4 zero | 1024 data | 4 zero]
#define KIN   704    // im2col K for in-conv (100*7 -> pad 704)

typedef __bf16 bf16x8 __attribute__((ext_vector_type(8)));
typedef float f32x4 __attribute__((ext_vector_type(4)));
typedef short s16x8 __attribute__((ext_vector_type(8)));
typedef short s16x4 __attribute__((ext_vector_type(4)));

__device__ __forceinline__ short f2b(float f) {
  unsigned u = __float_as_uint(f);
  u += 0x7fffu + ((u >> 16) & 1u);
  return (short)(u >> 16);
}
__device__ __forceinline__ float b2f(short s) {
  return __uint_as_float(((unsigned)(unsigned short)s) << 16);
}

// fast tanh-GELU (odd-symmetric, overflow-safe); |err| vs exact-erf ~1.5e-3
__device__ __forceinline__ float fast_gelu(float x) {
  float ax = fabsf(x);
  float z = 0.7978845608f * ax * (1.f + 0.044715f * ax * ax);
  float e = __expf(-2.f * z);
  float th = 1.f - 2.f * e * __builtin_amdgcn_rcpf(1.f + e);  // tanh(z) >= 0
  float g = copysignf(th, x);
  return 0.5f * x * (1.f + g);
}

__device__ __forceinline__ void gl2lds16(const void* g, void* l) {
  __builtin_amdgcn_global_load_lds(
      (__attribute__((address_space(1))) void*)g,
      (__attribute__((address_space(3))) void*)l, 16, 0, 0);
}

// ---------------- weight fp32 -> bf16, vectorized (n % 4 == 0) --------------
__global__ __launch_bounds__(256) void k_cvt4(const float* __restrict__ s,
                                              short* __restrict__ d, int n4) {
  for (int i = blockIdx.x * 256 + threadIdx.x; i < n4; i += gridDim.x * 256) {
    f32x4 v = *reinterpret_cast<const f32x4*>(&s[i * 4]);
    s16x4 o = {f2b(v[0]), f2b(v[1]), f2b(v[2]), f2b(v[3])};
    *reinterpret_cast<s16x4*>(&d[i * 4]) = o;
  }
}

// ov_w[c][n][k] -> ovb[k][c][n] bf16 (coalesced read 16B, 4 coalesced planes)
__global__ __launch_bounds__(256) void k_cvt_ov(const float* __restrict__ w,
                                                short* __restrict__ d) {
  const int n = HOP_ * NFFT_;   // (c,n) pairs
  for (int i = blockIdx.x * 256 + threadIdx.x; i < n; i += gridDim.x * 256) {
    f32x4 v = *reinterpret_cast<const f32x4*>(&w[(size_t)i * 4]);
#pragma unroll
    for (int k = 0; k < 4; ++k) d[(size_t)k * n + i] = f2b(v[k]);
  }
}

// in_w[c][ci][k] (700 contiguous per c) -> wib[c][704] bf16, pad 0
__global__ __launch_bounds__(256) void k_cvt_inw(const float* __restrict__ w,
                                                 short* __restrict__ d) {
  const int n = CH_ * KIN;
  for (int i = blockIdx.x * 256 + threadIdx.x; i < n; i += gridDim.x * 256) {
    int c = i / KIN, e = i - c * KIN;
    d[i] = (e < 700) ? f2b(w[c * 700 + e]) : (short)0;
  }
}

// dw_w [NL][512][7] fp32 -> dwt [NL][7][512] fp32
__global__ __launch_bounds__(256) void k_cvt_dwt(const float* __restrict__ w,
                                                 float* __restrict__ d) {
  const int n = NL_ * 7 * CH_;
  for (int i = blockIdx.x * 256 + threadIdx.x; i < n; i += gridDim.x * 256) {
    int l = i / (7 * CH_), r = i - l * 7 * CH_;
    int k = r >> 9, c = r & 511;
    d[i] = w[((size_t)l * CH_ + c) * 7 + k];
  }
}

// x[b][ci][t] fp32 -> xim[b*T+t][ci*7+k] = x[b,ci,t+k-3] bf16 (0 pad)
__global__ __launch_bounds__(256) void k_im2col(const float* __restrict__ x,
                                                short* __restrict__ xim) {
  const int total = BT * KIN;
  for (int i = blockIdx.x * 256 + threadIdx.x; i < total; i += gridDim.x * 256) {
    int m = i / KIN, e = i - m * KIN;
    int b = m >> 10, t = m & 1023;
    int ci = e / 7, k = e - ci * 7;
    int tt = t + k - 3;
    float v = (e < 700 && tt >= 0 && tt < T_) ? x[((b * CIN + ci) << 10) + tt] : 0.f;
    xim[i] = f2b(v);
  }
}

// zero the 4+4 pad rows of o1p per batch
__global__ __launch_bounds__(256) void k_zeropad(short* __restrict__ o1p) {
  int i = blockIdx.x * 256 + threadIdx.x;  // 131072
  int b = i >> 13;
  int r8 = (i >> 10) & 7;
  int nn = i & 1023;
  int row = r8 < 4 ? r8 : (OROWS - 8 + r8);
  o1p[((size_t)b * OROWS + row) * NFFT_ + nn] = 0;
}

// ---------------- layernorm bf16 -> bf16 (row of 512) -----------------------
__global__ __launch_bounds__(256) void k_lnb(const short* __restrict__ in,
                                             short* __restrict__ outp,
                                             const float* __restrict__ g,
                                             const float* __restrict__ bta) {
  int row = blockIdx.x, tid = threadIdx.x;
  unsigned u = *reinterpret_cast<const unsigned*>(&in[(size_t)row * CH_ + tid * 2]);
  float v0 = __uint_as_float(u << 16);
  float v1 = __uint_as_float(u & 0xffff0000u);
  float s = v0 + v1, q = v0 * v0 + v1 * v1;
#pragma unroll
  for (int o = 32; o > 0; o >>= 1) { s += __shfl_down(s, o); q += __shfl_down(q, o); }
  __shared__ float sh[8];
  int wid = tid >> 6, lane = tid & 63;
  if (lane == 0) { sh[wid] = s; sh[wid + 4] = q; }
  __syncthreads();
  float S = sh[0] + sh[1] + sh[2] + sh[3];
  float Q = sh[4] + sh[5] + sh[6] + sh[7];
  float mu  = S * (1.f / 512.f);
  float var = Q * (1.f / 512.f) - mu * mu;
  float r = rsqrtf(var + 1e-5f);
  float x0 = (v0 - mu) * r * g[tid * 2]     + bta[tid * 2];
  float x1 = (v1 - mu) * r * g[tid * 2 + 1] + bta[tid * 2 + 1];
  unsigned o = ((unsigned)(unsigned short)f2b(x0)) |
               (((unsigned)(unsigned short)f2b(x1)) << 16);
  *reinterpret_cast<unsigned*>(&outp[(size_t)row * CH_ + tid * 2]) = o;
}

// ---------------- fused depthwise 7-tap + LN, bf16, wave-per-row ------------
__global__ __launch_bounds__(256) void k_dwln(const short* __restrict__ h,
                                              const float* __restrict__ dwt,  // [7][512]
                                              const float* __restrict__ dwb,
                                              const float* __restrict__ g,
                                              const float* __restrict__ bta,
                                              short* __restrict__ yb) {
  int b = blockIdx.x, t0 = blockIdx.y * 32;
  int tid = threadIdx.x, lane = tid & 63, w = tid >> 6;
  __shared__ short hs[38][512];
  for (int e = tid; e < 38 * 64; e += 256) {
    int row = e >> 6, seg = (e & 63) << 3;
    int t = t0 - 3 + row;
    s16x8 v = {};
    if (t >= 0 && t < T_)
      v = *reinterpret_cast<const s16x8*>(&h[((size_t)((b << 10) + t)) * CH_ + seg]);
    *reinterpret_cast<s16x8*>(&hs[row][seg]) = v;
  }
  const int c0 = lane << 3;
  float wk[7][8];
#pragma unroll
  for (int k = 0; k < 7; ++k) {
    f32x4 lo = *reinterpret_cast<const f32x4*>(&dwt[k * CH_ + c0]);
    f32x4 hi = *reinterpret_cast<const f32x4*>(&dwt[k * CH_ + c0 + 4]);
#pragma unroll
    for (int j = 0; j < 4; ++j) { wk[k][j] = lo[j]; wk[k][j + 4] = hi[j]; }
  }
  float bb[8], gg[8], be[8];
  {
    f32x4 a = *reinterpret_cast<const f32x4*>(&dwb[c0]);
    f32x4 b4 = *reinterpret_cast<const f32x4*>(&dwb[c0 + 4]);
    f32x4 c = *reinterpret_cast<const f32x4*>(&g[c0]);
    f32x4 d = *reinterpret_cast<const f32x4*>(&g[c0 + 4]);
    f32x4 e = *reinterpret_cast<const f32x4*>(&bta[c0]);
    f32x4 f = *reinterpret_cast<const f32x4*>(&bta[c0 + 4]);
#pragma unroll
    for (int j = 0; j < 4; ++j) {
      bb[j] = a[j]; bb[j + 4] = b4[j];
      gg[j] = c[j]; gg[j + 4] = d[j];
      be[j] = e[j]; be[j + 4] = f[j];
    }
  }
  __syncthreads();
#pragma unroll
  for (int i = 0; i < 8; ++i) {
    int r = w * 8 + i;
    float acc[8];
#pragma unroll
    for (int j = 0; j < 8; ++j) acc[j] = bb[j];
#pragma unroll
    for (int k = 0; k < 7; ++k) {
      s16x8 hv = *reinterpret_cast<const s16x8*>(&hs[r + k][c0]);
#pragma unroll
      for (int j = 0; j < 8; ++j) acc[j] += b2f(hv[j]) * wk[k][j];
    }
    float s = 0.f, q = 0.f;
#pragma unroll
    for (int j = 0; j < 8; ++j) { s += acc[j]; q += acc[j] * acc[j]; }
#pragma unroll
    for (int o = 32; o > 0; o >>= 1) { s += __shfl_xor(s, o); q += __shfl_xor(q, o); }
    float mu  = s * (1.f / 512.f);
    float var = q * (1.f / 512.f) - mu * mu;
    float rr = rsqrtf(var + 1e-5f);
    s16x8 ov;
#pragma unroll
    for (int j = 0; j < 8; ++j) ov[j] = f2b((acc[j] - mu) * rr * gg[j] + be[j]);
    *reinterpret_cast<s16x8*>(&yb[((size_t)((b << 10) + t0 + r)) * CH_ + c0]) = ov;
  }
}

// ---------------- bf16 MFMA GEMM (128x128, modes 0/2) -----------------------
// 2-phase double-buffered; used for inconv (K=704) and pw2 (N=512).
// MODE 0: obf = bf16(acc+bias)
// MODE 2: obf[m][n] = bf16(obf + bf16((acc+bias)*scale))   (residual RMW)
template <int MODE>
__global__ __launch_bounds__(256) void k_mgemm(const short* __restrict__ A,
                                               const short* __restrict__ Bw,
                                               const float* __restrict__ bias,
                                               const float* __restrict__ scale,
                                               short* __restrict__ obf,
                                               int N, int K) {
  __shared__ __align__(16) short smem[4 * 128 * 64];   // 64KB: 2 bufs x (A|B)
  const int tid = threadIdx.x;
  const int lane = tid & 63, w = tid >> 6;
  const int id = blockIdx.x;
  const int ny = N >> 7;
  const int g8 = id >> 3;
  const int gq = g8 / ny;
  const int mt = (id & 7) + (gq << 3);
  const int nt_ = g8 - gq * ny;
  const int m0 = mt << 7, n0 = nt_ << 7;
  const int wr = (w >> 1) * 64, wc = (w & 1) * 64;
  f32x4 acc[4][4];
#pragma unroll
  for (int i = 0; i < 4; ++i)
#pragma unroll
    for (int j = 0; j < 4; ++j) acc[i][j] = (f32x4){0.f, 0.f, 0.f, 0.f};

  const short* Ab = A + (size_t)m0 * K;
  const short* Bb = Bw + (size_t)n0 * K;
  int r_[4], kk_[4];
#pragma unroll
  for (int j = 0; j < 4; ++j) {
    int c = tid + j * 256;
    r_[j] = c >> 3;
    kk_[j] = (((c & 7) ^ (r_[j] & 7)) * 8);   // inverse-swizzled source (rule #21)
  }
  const int ar = wr + (lane & 15);
  const int br = wc + (lane & 15);
  const int hi = lane >> 4;
  const int nsteps = K >> 6;

  auto stage = [&](int buf, int k0) {
    short* Sa = smem + buf * 16384;
    short* Sb = Sa + 8192;
#pragma unroll
    for (int j = 0; j < 4; ++j)
      gl2lds16(Ab + (size_t)r_[j] * K + k0 + kk_[j], Sa + (j * 256 + w * 64) * 8);
#pragma unroll
    for (int j = 0; j < 4; ++j)
      gl2lds16(Bb + (size_t)r_[j] * K + k0 + kk_[j], Sb + (j * 256 + w * 64) * 8);
  };

  stage(0, 0);
  asm volatile("s_waitcnt vmcnt(0)" ::: "memory");
  __syncthreads();
  for (int t = 0; t < nsteps; ++t) {
    const int cur = t & 1;
    if (t + 1 < nsteps) stage(cur ^ 1, (t + 1) << 6);   // prefetch next tile
    const short* As = smem + cur * 16384;
    const short* Bs = As + 8192;
#pragma unroll
    for (int ks = 0; ks < 2; ++ks) {
      bf16x8 a[4], b[4];
#pragma unroll
      for (int f = 0; f < 4; ++f) {
        int row = ar + f * 16;
        a[f] = *reinterpret_cast<const bf16x8*>(&As[row * 64 + (((ks * 4 + hi) ^ (row & 7)) * 8)]);
      }
#pragma unroll
      for (int f = 0; f < 4; ++f) {
        int row = br + f * 16;
        b[f] = *reinterpret_cast<const bf16x8*>(&Bs[row * 64 + (((ks * 4 + hi) ^ (row & 7)) * 8)]);
      }
#pragma unroll
      for (int fi = 0; fi < 4; ++fi)
#pragma unroll
        for (int fj = 0; fj < 4; ++fj)
          acc[fi][fj] = __builtin_amdgcn_mfma_f32_16x16x32_bf16(a[fi], b[fj], acc[fi][fj], 0, 0, 0);
    }
    asm volatile("s_waitcnt vmcnt(0)" ::: "memory");
    __syncthreads();
  }
  // ---- epilogue: acc -> LDS -> coalesced 16B stores ----
  short* Cl = smem;
  const int colbase = wc + (lane & 15);
#pragma unroll
  for (int fj = 0; fj < 4; ++fj) {
    int cl = colbase + fj * 16;
    int n = n0 + cl;
    float bi = bias[n];
    float sc = (MODE == 2) ? scale[n] : 0.f;
#pragma unroll
    for (int fi = 0; fi < 4; ++fi) {
#pragma unroll
      for (int r = 0; r < 4; ++r) {
        int rl = wr + (hi << 2) + fi * 16 + r;
        float v = acc[fi][fj][r] + bi;
        if (MODE == 2) v *= sc;
        Cl[rl * 128 + (cl ^ (((rl >> 2) & 3) << 4))] = f2b(v);
      }
    }
  }
  __syncthreads();
  const int cs = (lane & 15) * 8;
#pragma unroll
  for (int it = 0; it < 8; ++it) {
    int rl = w * 32 + it * 4 + (lane >> 4);
    s16x8 v = *reinterpret_cast<const s16x8*>(&Cl[rl * 128 + (cs ^ (((rl >> 2) & 3) << 4))]);
    int m = m0 + rl;
    if (MODE == 2) {
      size_t idx = (size_t)m * N + n0 + cs;
      s16x8 hv = *reinterpret_cast<const s16x8*>(&obf[idx]);
      s16x8 o;
#pragma unroll
      for (int j = 0; j < 8; ++j) o[j] = f2b(b2f(hv[j]) + b2f(v[j]));
      *reinterpret_cast<s16x8*>(&obf[idx]) = o;
    } else {
      *reinterpret_cast<s16x8*>(&obf[(size_t)m * N + n0 + cs]) = v;
    }
  }
}

// ---------------- 256x256 8-wave GEMM, counted-vmcnt 2-deep pipeline --------
// MODE 1: obf = bf16(gelu(acc+bias))         [M][N]
// MODE 3: obf = bf16(acc+bias) at padded o1 rows (b*OROWS+4+t), stride NFFT
// K-tiles of 64; prologue stages kt0,kt1; stage(kt+2) issued at qt==3 after a
// read-fence barrier; entry wait vmcnt(8) keeps next tile's loads in flight.
template <int MODE>
__global__ __launch_bounds__(512, 2) void k_mg256(const short* __restrict__ A,
                                                  const short* __restrict__ Bw,
                                                  const float* __restrict__ bias,
                                                  short* __restrict__ obf,
                                                  int N, int K) {
  constexpr int BM = 256, BN = 256;
  __shared__ __align__(16) short smem[2 * (BM + BN) * 64];   // 128KB
  const int tid = threadIdx.x;
  const int lane = tid & 63, w = tid >> 6;       // w in 0..7
  const int wm = w >> 2, wn = w & 3;             // 2 x 4 wave grid
  const int id = blockIdx.x;
  const int ny = N >> 8;
  const int g8 = id >> 3, gq = g8 / ny;
  const int mt = (id & 7) + (gq << 3);
  const int nt = g8 - gq * ny;
  const int m0 = mt << 8, n0 = nt << 8;

  f32x4 acc[8][4] = {};
  const short* Ag = A + (size_t)m0 * K;
  const short* Bg = Bw + (size_t)n0 * K;
  short* bufA[2]; short* bufB[2];
  bufA[0] = smem;                   bufB[0] = smem + BM * 64;
  bufA[1] = smem + (BM + BN) * 64;  bufB[1] = bufA[1] + BM * 64;

  auto stage = [&](int buf, int k0) {
#pragma unroll
    for (int j = 0; j < 4; ++j) {           // A: 256 rows x 8 chunks
      int c = tid + j * 512;
      int row = c >> 3, ch = (c & 7) ^ (row & 7);
      gl2lds16(Ag + (size_t)row * K + k0 + ch * 8, bufA[buf] + (j * 512 + w * 64) * 8);
    }
#pragma unroll
    for (int j = 0; j < 4; ++j) {           // B: 256 rows x 8 chunks
      int c = tid + j * 512;
      int row = c >> 3, ch = (c & 7) ^ (row & 7);
      gl2lds16(Bg + (size_t)row * K + k0 + ch * 8, bufB[buf] + (j * 512 + w * 64) * 8);
    }
  };

  const int nkt = K >> 6;
  stage(0, 0);
  stage(1, 64);
  const int arow0 = wm * 128 + (lane & 15);
  const int brow0 = wn * 64 + (lane & 15);
  const int hi = lane >> 4;

  for (int kt = 0; kt < nkt; ++kt) {
    const int buf = kt & 1;
    if (kt + 1 < nkt) asm volatile("s_waitcnt vmcnt(8)" ::: "memory");
    else              asm volatile("s_waitcnt vmcnt(0)" ::: "memory");
    __builtin_amdgcn_s_barrier();
    bf16x8 bf[4][2];
#pragma unroll
    for (int f = 0; f < 4; ++f)
#pragma unroll
      for (int ks = 0; ks < 2; ++ks) {
        int row = brow0 + f * 16;
        bf[f][ks] = *reinterpret_cast<const bf16x8*>(
            &bufB[buf][row * 64 + (((ks * 4 + hi) ^ (row & 7)) * 8)]);
      }
#pragma unroll
    for (int qt = 0; qt < 4; ++qt) {
      bf16x8 af[2][2];
#pragma unroll
      for (int f = 0; f < 2; ++f)
#pragma unroll
        for (int ks = 0; ks < 2; ++ks) {
          int row = arow0 + (qt * 2 + f) * 16;
          af[f][ks] = *reinterpret_cast<const bf16x8*>(
              &bufA[buf][row * 64 + (((ks * 4 + hi) ^ (row & 7)) * 8)]);
        }
      if (qt == 3) {
        // all reads of buf retired -> safe to overwrite with kt+2's stage
        asm volatile("s_waitcnt lgkmcnt(0)" ::: "memory");
        __builtin_amdgcn_sched_barrier(0);
        __builtin_amdgcn_s_barrier();
        if (kt + 2 < nkt) stage(buf, (kt + 2) << 6);
      }
#pragma unroll
      for (int f = 0; f < 2; ++f)
#pragma unroll
        for (int fj = 0; fj < 4; ++fj)
#pragma unroll
          for (int ks = 0; ks < 2; ++ks)
            acc[qt * 2 + f][fj] = __builtin_amdgcn_mfma_f32_16x16x32_bf16(
                af[f][ks], bf[fj][ks], acc[qt * 2 + f][fj], 0, 0, 0);
    }
  }
  // ---- epilogue: stage C (256x256 bf16 = full 128KB smem), coalesced out ---
  asm volatile("s_waitcnt lgkmcnt(0)" ::: "memory");
  __builtin_amdgcn_s_barrier();
  short* Cl = smem;
  const int clb = wn * 64 + (lane & 15);
#pragma unroll
  for (int fj = 0; fj < 4; ++fj) {
    int cl = clb + fj * 16;
    float bi = bias[n0 + cl];
#pragma unroll
    for (int fi = 0; fi < 8; ++fi) {
#pragma unroll
      for (int r = 0; r < 4; ++r) {
        int rl = wm * 128 + fi * 16 + (hi << 2) + r;
        float v = acc[fi][fj][r] + bi;
        if (MODE == 1) v = fast_gelu(v);
        Cl[rl * 256 + (cl ^ ((rl & 15) << 4))] = f2b(v);
      }
    }
  }
  __syncthreads();
#pragma unroll
  for (int it = 0; it < 16; ++it) {
    int gc = it * 512 + tid;
    int row = gc >> 5, ch = gc & 31;
    int ec = (ch * 8) ^ ((row & 15) << 4);
    s16x8 v = *reinterpret_cast<const s16x8*>(&Cl[row * 256 + ec]);
    int m = m0 + row;
    if (MODE == 3) {
      int bb = m >> 10, t = m & 1023;
      *reinterpret_cast<s16x8*>(
          &obf[((size_t)(bb * OROWS + 4 + t)) * NFFT_ + n0 + ch * 8]) = v;
    } else {
      *reinterpret_cast<s16x8*>(&obf[(size_t)m * N + n0 + ch * 8]) = v;
    }
  }
}

// ---------------- overlap conv: 128(l)x64(c) tiles, A+B double-buffered -----
__global__ __launch_bounds__(256) void k_ovgemm(const short* __restrict__ o1p,
                                                const short* __restrict__ ovb,
                                                float* __restrict__ o2) {
  __shared__ __align__(16) short As2[2][136 * 64];
  __shared__ __align__(16) short Bs2[2][64 * 64];
  const int tid = threadIdx.x;
  const int lane = tid & 63, w = tid >> 6;
  const int l0 = blockIdx.x * 128, c0 = blockIdx.y * 64, b = blockIdx.z;
  const int wr = (w >> 1) * 64, wc = (w & 1) * 32;
  f32x4 acc[4][2];
#pragma unroll
  for (int i = 0; i < 4; ++i)
#pragma unroll
    for (int j = 0; j < 2; ++j) acc[i][j] = (f32x4){0.f, 0.f, 0.f, 0.f};

  const short* Ab = o1p + (size_t)b * OROWS * NFFT_;
  const int ar = wr + (lane & 15);
  const int br = wc + (lane & 15);
  const int hi = lane >> 4;
  const int sl_row = lane >> 3;
  const int sl_j   = lane & 7;
  int br_[2], bk_[2];
#pragma unroll
  for (int j = 0; j < 2; ++j) {
    int c = tid + j * 256;
    br_[j] = c >> 3;
    bk_[j] = ((c & 7) ^ (br_[j] & 7)) * 8;
  }

  auto stageA = [&](int buf, int k0) {
    for (int cg = w; cg < 17; cg += 4) {
      int lr = cg * 8 + sl_row;
      int gr = l0 + 1 + lr;
      if (gr > OROWS - 1) gr = OROWS - 1;
      int j = sl_j ^ (lr & 7);
      gl2lds16(Ab + (size_t)gr * NFFT_ + k0 + j * 8, &As2[buf][cg * 512]);
    }
  };
  auto stageB = [&](int buf, int k0, int ksh) {
    const short* Bb = ovb + ((size_t)(ksh * HOP_ + c0)) * NFFT_;
#pragma unroll
    for (int j = 0; j < 2; ++j)
      gl2lds16(Bb + (size_t)br_[j] * NFFT_ + k0 + bk_[j],
               &Bs2[buf][(j * 256 + w * 64) * 8]);
  };

  int ab = 0, bb = 0;
  stageA(0, 0);
  stageB(0, 0, 0);
  asm volatile("s_waitcnt vmcnt(0)" ::: "memory");
  __syncthreads();
  for (int t = 0; t < 64; ++t) {            // 16 k0-steps x 4 ksh
    const int ksh = t & 3;
    const int nt = t + 1;
    if (nt < 64) {
      int nk0 = (nt >> 2) << 6;
      if ((nt & 3) == 0) stageA(ab ^ 1, nk0);
      stageB(bb ^ 1, nk0, nt & 3);
    }
    const short* As = As2[ab];
    const short* Bs = Bs2[bb];
#pragma unroll
    for (int ks = 0; ks < 2; ++ks) {
      bf16x8 a[4], bfr[2];
#pragma unroll
      for (int f = 0; f < 4; ++f) {
        int row = ar + f * 16 + ksh;
        a[f] = *reinterpret_cast<const bf16x8*>(&As[row * 64 + (((ks * 4 + hi) ^ (row & 7)) * 8)]);
      }
#pragma unroll
      for (int f = 0; f < 2; ++f) {
        int row = br + f * 16;
        bfr[f] = *reinterpret_cast<const bf16x8*>(&Bs[row * 64 + (((ks * 4 + hi) ^ (row & 7)) * 8)]);
      }
#pragma unroll
      for (int fi = 0; fi < 4; ++fi)
#pragma unroll
        for (int fj = 0; fj < 2; ++fj)
          acc[fi][fj] = __builtin_amdgcn_mfma_f32_16x16x32_bf16(a[fi], bfr[fj], acc[fi][fj], 0, 0, 0);
    }
    asm volatile("s_waitcnt vmcnt(0)" ::: "memory");
    __syncthreads();
    bb ^= 1;
    if (ksh == 3) ab ^= 1;
  }
  const int lb = l0 + wr + (hi << 2);
  const int cb = c0 + wc + (lane & 15);
#pragma unroll
  for (int fj = 0; fj < 2; ++fj) {
    int c = cb + fj * 16;
#pragma unroll
    for (int fi = 0; fi < 4; ++fi) {
#pragma unroll
      for (int r = 0; r < 4; ++r) {
        int l = lb + fi * 16 + r;
        if (l < L_) o2[((size_t)b * L_ + l) * HOP_ + c] = acc[fi][fj][r];
      }
    }
  }
}

// ---------------- final gather-sum over o2[b][l][c] -------------------------
__global__ __launch_bounds__(256) void k_oadd(const float* __restrict__ o2,
                                              float* __restrict__ out) {
  int b = blockIdx.x;
  int t = blockIdx.y * 256 + threadIdx.x;
  int m = t + 2;
  float s = 0.f;
  for (int c = 0; c < HOP_; ++c) {
    s += o2[((size_t)b * L_ + m) * HOP_ + c];
    m -= 4;
    if (m < 0) m += L_;
  }
  out[b * T_ + t] = s;
}

extern "C" void kernel_launch(void* const* d_in, const int* in_sizes, int n_in,
                              void* d_out, int out_size, void* d_ws, size_t ws_size,
                              hipStream_t stream) {
  const float* x      = (const float*)d_in[0];
  const float* in_w   = (const float*)d_in[1];
  const float* in_b   = (const float*)d_in[2];
  const float* norm_g = (const float*)d_in[3];
  const float* norm_b = (const float*)d_in[4];
  const float* dw_w   = (const float*)d_in[5];
  const float* dw_b   = (const float*)d_in[6];
  const float* ln_g   = (const float*)d_in[7];
  const float* ln_b   = (const float*)d_in[8];
  const float* pw1_w  = (const float*)d_in[9];
  const float* pw1_b  = (const float*)d_in[10];
  const float* pw2_w  = (const float*)d_in[11];
  const float* pw2_b  = (const float*)d_in[12];
  const float* ls     = (const float*)d_in[13];
  const float* normLg = (const float*)d_in[14];
  const float* normLb = (const float*)d_in[15];
  const float* out_w  = (const float*)d_in[16];
  const float* out_b  = (const float*)d_in[17];
  const float* ov_w   = (const float*)d_in[18];
  float* out = (float*)d_out;

  char* p = (char*)d_ws;
  short* hb   = (short*)p; p += (size_t)BT * CH_ * 2;        // 16.78 MB
  short* yb   = (short*)p; p += (size_t)BT * CH_ * 2;        // 16.78 MB
  short* zb   = (short*)p; p += (size_t)BT * HCH_ * 2;       // 50.33 MB
  short* pw1b = (short*)p; p += (size_t)NL_ * HCH_ * CH_ * 2;
  short* pw2b = (short*)p; p += (size_t)NL_ * CH_ * HCH_ * 2;
  short* owb  = (short*)p; p += (size_t)NFFT_ * CH_ * 2;
  short* ovb  = (short*)p; p += (size_t)4 * HOP_ * NFFT_ * 2;
  float* dwt  = (float*)p; p += (size_t)NL_ * 7 * CH_ * 4;
  short* xim  = zb;                        // alias: zb not yet used
  short* wib  = zb + (size_t)BT * KIN;     // fits (23.6 MB < 50.3 MB)
  short* hbL  = yb;                        // alias: yb dead when final LN runs
  short* o1p  = zb;                        // alias: zb dead after layer loop
  float* o2   = (float*)hb;                // spans hb + start of yb; both dead

  k_cvt4<<<4096, 256, 0, stream>>>(pw1_w, pw1b, NL_ * HCH_ * CH_ / 4);
  k_cvt4<<<4096, 256, 0, stream>>>(pw2_w, pw2b, NL_ * CH_ * HCH_ / 4);
  k_cvt4<<<512, 256, 0, stream>>>(out_w, owb, NFFT_ * CH_ / 4);
  k_cvt_ov<<<1024, 256, 0, stream>>>(ov_w, ovb);
  k_cvt_inw<<<1408, 256, 0, stream>>>(in_w, wib);
  k_cvt_dwt<<<112, 256, 0, stream>>>(dw_w, dwt);
  k_im2col<<<8192, 256, 0, stream>>>(x, xim);

  k_mgemm<0><<<512, 256, 0, stream>>>(xim, wib, in_b, nullptr, hb, CH_, KIN);
  k_lnb<<<BT, 256, 0, stream>>>(hb, hb, norm_g, norm_b);
  for (int l = 0; l < NL_; ++l) {
    k_dwln<<<dim3(B_, T_ / 32), 256, 0, stream>>>(
        hb, dwt + (size_t)l * 7 * CH_, dw_b + l * CH_,
        ln_g + l * CH_, ln_b + l * CH_, yb);
    k_mg256<1><<<384, 512, 0, stream>>>(
        yb, pw1b + (size_t)l * HCH_ * CH_, pw1_b + l * HCH_, zb, HCH_, CH_);
    k_mgemm<2><<<512, 256, 0, stream>>>(
        zb, pw2b + (size_t)l * CH_ * HCH_, pw2_b + l * CH_, ls + l * CH_, hb,
        CH_, HCH_);
  }
  k_lnb<<<BT, 256, 0, stream>>>(hb, hbL, normLg, normLb);
  k_mg256<3><<<256, 512, 0, stream>>>(hbL, owb, out_b, o1p, NFFT_, CH_);
  k_zeropad<<<512, 256, 0, stream>>>(o1p);
  k_ovgemm<<<dim3(9, 4, 16), 256, 0, stream>>>(o1p, ovb, o2);
  k_oadd<<<dim3(B_, 4), 256, 0, stream>>>(o2, out);
}

// Round 11
// 906.841 us; speedup vs baseline: 1.1575x; 1.1575x over previous
//
#include <hip/hip_runtime.h>

#define B_    16
#define CIN   100
#define T_    1024
#define CH_   512
#define HCH_  1536
#define NL_   8
#define NFFT_ 1024
#define HOP_  256
#define BT    (B_ * T_)
#define L_    1027
#define OROWS 1032   // padded o1 rows per batch: [4 zero | 1024 data | 4 zero]
#define KIN   704    // im2col K for in-conv (100*7 -> pad 704)

typedef __bf16 bf16x8 __attribute__((ext_vector_type(8)));
typedef float f32x4 __attribute__((ext_vector_type(4)));
typedef short s16x8 __attribute__((ext_vector_type(8)));
typedef short s16x4 __attribute__((ext_vector_type(4)));

__device__ __forceinline__ short f2b(float f) {
  unsigned u = __float_as_uint(f);
  u += 0x7fffu + ((u >> 16) & 1u);
  return (short)(u >> 16);
}
__device__ __forceinline__ float b2f(short s) {
  return __uint_as_float(((unsigned)(unsigned short)s) << 16);
}

// fast tanh-GELU (odd-symmetric, overflow-safe); |err| vs exact-erf ~1.5e-3
__device__ __forceinline__ float fast_gelu(float x) {
  float ax = fabsf(x);
  float z = 0.7978845608f * ax * (1.f + 0.044715f * ax * ax);
  float e = __expf(-2.f * z);
  float th = 1.f - 2.f * e * __builtin_amdgcn_rcpf(1.f + e);  // tanh(z) >= 0
  float g = copysignf(th, x);
  return 0.5f * x * (1.f + g);
}

__device__ __forceinline__ void gl2lds16(const void* g, void* l) {
  __builtin_amdgcn_global_load_lds(
      (__attribute__((address_space(1))) void*)g,
      (__attribute__((address_space(3))) void*)l, 16, 0, 0);
}

// ---------------- weight fp32 -> bf16, vectorized (n % 4 == 0) --------------
__global__ __launch_bounds__(256) void k_cvt4(const float* __restrict__ s,
                                              short* __restrict__ d, int n4) {
  for (int i = blockIdx.x * 256 + threadIdx.x; i < n4; i += gridDim.x * 256) {
    f32x4 v = *reinterpret_cast<const f32x4*>(&s[i * 4]);
    s16x4 o = {f2b(v[0]), f2b(v[1]), f2b(v[2]), f2b(v[3])};
    *reinterpret_cast<s16x4*>(&d[i * 4]) = o;
  }
}

// ov_w[c][n][k] -> ovb[k][c][n] bf16 (coalesced read 16B, 4 coalesced planes)
__global__ __launch_bounds__(256) void k_cvt_ov(const float* __restrict__ w,
                                                short* __restrict__ d) {
  const int n = HOP_ * NFFT_;   // (c,n) pairs
  for (int i = blockIdx.x * 256 + threadIdx.x; i < n; i += gridDim.x * 256) {
    f32x4 v = *reinterpret_cast<const f32x4*>(&w[(size_t)i * 4]);
#pragma unroll
    for (int k = 0; k < 4; ++k) d[(size_t)k * n + i] = f2b(v[k]);
  }
}

// in_w[c][ci][k] (700 contiguous per c) -> wib[c][704] bf16, pad 0
__global__ __launch_bounds__(256) void k_cvt_inw(const float* __restrict__ w,
                                                 short* __restrict__ d) {
  const int n = CH_ * KIN;
  for (int i = blockIdx.x * 256 + threadIdx.x; i < n; i += gridDim.x * 256) {
    int c = i / KIN, e = i - c * KIN;
    d[i] = (e < 700) ? f2b(w[c * 700 + e]) : (short)0;
  }
}

// dw_w [NL][512][7] fp32 -> dwt [NL][7][512] fp32
__global__ __launch_bounds__(256) void k_cvt_dwt(const float* __restrict__ w,
                                                 float* __restrict__ d) {
  const int n = NL_ * 7 * CH_;
  for (int i = blockIdx.x * 256 + threadIdx.x; i < n; i += gridDim.x * 256) {
    int l = i / (7 * CH_), r = i - l * 7 * CH_;
    int k = r >> 9, c = r & 511;
    d[i] = w[((size_t)l * CH_ + c) * 7 + k];
  }
}

// x[b][ci][t] fp32 -> xim[b*T+t][ci*7+k] = x[b,ci,t+k-3] bf16 (0 pad)
__global__ __launch_bounds__(256) void k_im2col(const float* __restrict__ x,
                                                short* __restrict__ xim) {
  const int total = BT * KIN;
  for (int i = blockIdx.x * 256 + threadIdx.x; i < total; i += gridDim.x * 256) {
    int m = i / KIN, e = i - m * KIN;
    int b = m >> 10, t = m & 1023;
    int ci = e / 7, k = e - ci * 7;
    int tt = t + k - 3;
    float v = (e < 700 && tt >= 0 && tt < T_) ? x[((b * CIN + ci) << 10) + tt] : 0.f;
    xim[i] = f2b(v);
  }
}

// zero the 4+4 pad rows of o1p per batch
__global__ __launch_bounds__(256) void k_zeropad(short* __restrict__ o1p) {
  int i = blockIdx.x * 256 + threadIdx.x;  // 131072
  int b = i >> 13;
  int r8 = (i >> 10) & 7;
  int nn = i & 1023;
  int row = r8 < 4 ? r8 : (OROWS - 8 + r8);
  o1p[((size_t)b * OROWS + row) * NFFT_ + nn] = 0;
}

// ---------------- layernorm bf16 -> bf16 (row of 512) -----------------------
__global__ __launch_bounds__(256) void k_lnb(const short* __restrict__ in,
                                             short* __restrict__ outp,
                                             const float* __restrict__ g,
                                             const float* __restrict__ bta) {
  int row = blockIdx.x, tid = threadIdx.x;
  unsigned u = *reinterpret_cast<const unsigned*>(&in[(size_t)row * CH_ + tid * 2]);
  float v0 = __uint_as_float(u << 16);
  float v1 = __uint_as_float(u & 0xffff0000u);
  float s = v0 + v1, q = v0 * v0 + v1 * v1;
#pragma unroll
  for (int o = 32; o > 0; o >>= 1) { s += __shfl_down(s, o); q += __shfl_down(q, o); }
  __shared__ float sh[8];
  int wid = tid >> 6, lane = tid & 63;
  if (lane == 0) { sh[wid] = s; sh[wid + 4] = q; }
  __syncthreads();
  float S = sh[0] + sh[1] + sh[2] + sh[3];
  float Q = sh[4] + sh[5] + sh[6] + sh[7];
  float mu  = S * (1.f / 512.f);
  float var = Q * (1.f / 512.f) - mu * mu;
  float r = rsqrtf(var + 1e-5f);
  float x0 = (v0 - mu) * r * g[tid * 2]     + bta[tid * 2];
  float x1 = (v1 - mu) * r * g[tid * 2 + 1] + bta[tid * 2 + 1];
  unsigned o = ((unsigned)(unsigned short)f2b(x0)) |
               (((unsigned)(unsigned short)f2b(x1)) << 16);
  *reinterpret_cast<unsigned*>(&outp[(size_t)row * CH_ + tid * 2]) = o;
}

// ---------------- fused depthwise 7-tap + LN, bf16, wave-per-row ------------
__global__ __launch_bounds__(256) void k_dwln(const short* __restrict__ h,
                                              const float* __restrict__ dwt,  // [7][512]
                                              const float* __restrict__ dwb,
                                              const float* __restrict__ g,
                                              const float* __restrict__ bta,
                                              short* __restrict__ yb) {
  int b = blockIdx.x, t0 = blockIdx.y * 32;
  int tid = threadIdx.x, lane = tid & 63, w = tid >> 6;
  __shared__ short hs[38][512];
  for (int e = tid; e < 38 * 64; e += 256) {
    int row = e >> 6, seg = (e & 63) << 3;
    int t = t0 - 3 + row;
    s16x8 v = {};
    if (t >= 0 && t < T_)
      v = *reinterpret_cast<const s16x8*>(&h[((size_t)((b << 10) + t)) * CH_ + seg]);
    *reinterpret_cast<s16x8*>(&hs[row][seg]) = v;
  }
  const int c0 = lane << 3;
  float wk[7][8];
#pragma unroll
  for (int k = 0; k < 7; ++k) {
    f32x4 lo = *reinterpret_cast<const f32x4*>(&dwt[k * CH_ + c0]);
    f32x4 hi = *reinterpret_cast<const f32x4*>(&dwt[k * CH_ + c0 + 4]);
#pragma unroll
    for (int j = 0; j < 4; ++j) { wk[k][j] = lo[j]; wk[k][j + 4] = hi[j]; }
  }
  float bb[8], gg[8], be[8];
  {
    f32x4 a = *reinterpret_cast<const f32x4*>(&dwb[c0]);
    f32x4 b4 = *reinterpret_cast<const f32x4*>(&dwb[c0 + 4]);
    f32x4 c = *reinterpret_cast<const f32x4*>(&g[c0]);
    f32x4 d = *reinterpret_cast<const f32x4*>(&g[c0 + 4]);
    f32x4 e = *reinterpret_cast<const f32x4*>(&bta[c0]);
    f32x4 f = *reinterpret_cast<const f32x4*>(&bta[c0 + 4]);
#pragma unroll
    for (int j = 0; j < 4; ++j) {
      bb[j] = a[j]; bb[j + 4] = b4[j];
      gg[j] = c[j]; gg[j + 4] = d[j];
      be[j] = e[j]; be[j + 4] = f[j];
    }
  }
  __syncthreads();
#pragma unroll
  for (int i = 0; i < 8; ++i) {
    int r = w * 8 + i;
    float acc[8];
#pragma unroll
    for (int j = 0; j < 8; ++j) acc[j] = bb[j];
#pragma unroll
    for (int k = 0; k < 7; ++k) {
      s16x8 hv = *reinterpret_cast<const s16x8*>(&hs[r + k][c0]);
#pragma unroll
      for (int j = 0; j < 8; ++j) acc[j] += b2f(hv[j]) * wk[k][j];
    }
    float s = 0.f, q = 0.f;
#pragma unroll
    for (int j = 0; j < 8; ++j) { s += acc[j]; q += acc[j] * acc[j]; }
#pragma unroll
    for (int o = 32; o > 0; o >>= 1) { s += __shfl_xor(s, o); q += __shfl_xor(q, o); }
    float mu  = s * (1.f / 512.f);
    float var = q * (1.f / 512.f) - mu * mu;
    float rr = rsqrtf(var + 1e-5f);
    s16x8 ov;
#pragma unroll
    for (int j = 0; j < 8; ++j) ov[j] = f2b((acc[j] - mu) * rr * gg[j] + be[j]);
    *reinterpret_cast<s16x8*>(&yb[((size_t)((b << 10) + t0 + r)) * CH_ + c0]) = ov;
  }
}

// ---------------- bf16 MFMA GEMM: C[m,n] = sum_k A[m,k]*Bw[n,k] -------------
// 128x128 tile, 4 waves, 2-phase double-buffered pipeline, BK parameterized:
// BK=32 -> 32KB LDS (~5 blocks/CU, TLP hides per-step drain; for short K).
// BK=64 -> 64KB LDS (2 blocks/CU; for long K).
// XCD-grouped tile mapping; LDS-staged coalesced epilogue (16B stores).
// MODE 0: obf = bf16(acc+bias)
// MODE 1: obf = bf16(gelu(acc+bias))
// MODE 2: obf[m][n] = bf16(obf + bf16((acc+bias)*scale))   (residual RMW)
// MODE 3: obf = bf16(acc+bias) at padded o1 rows (b*OROWS+4+t), stride NFFT
template <int MODE, int BK>
__global__ __launch_bounds__(256) void k_mgemm(const short* __restrict__ A,
                                               const short* __restrict__ Bw,
                                               const float* __restrict__ bias,
                                               const float* __restrict__ scale,
                                               short* __restrict__ obf,
                                               int N, int K) {
  constexpr int CPR  = BK / 8;            // 16B chunks per row
  constexpr int NCH  = BK / 16;           // staging chunks per thread (A or B)
  constexpr int TILE = 128 * BK;          // shorts per A (or B) buf
  constexpr int SMEM = (4 * TILE > 16384) ? 4 * TILE : 16384;
  __shared__ __align__(16) short smem[SMEM];
  const int tid = threadIdx.x;
  const int lane = tid & 63, w = tid >> 6;
  const int id = blockIdx.x;
  const int ny = N >> 7;
  const int g8 = id >> 3;
  const int gq = g8 / ny;
  const int mt = (id & 7) + (gq << 3);
  const int nt_ = g8 - gq * ny;
  const int m0 = mt << 7, n0 = nt_ << 7;
  const int wr = (w >> 1) * 64, wc = (w & 1) * 64;
  f32x4 acc[4][4];
#pragma unroll
  for (int i = 0; i < 4; ++i)
#pragma unroll
    for (int j = 0; j < 4; ++j) acc[i][j] = (f32x4){0.f, 0.f, 0.f, 0.f};

  const short* Ab = A + (size_t)m0 * K;
  const short* Bb = Bw + (size_t)n0 * K;
  int r_[NCH], kk_[NCH];
#pragma unroll
  for (int j = 0; j < NCH; ++j) {
    int c = tid + j * 256;
    r_[j] = c / CPR;
    kk_[j] = (((c % CPR) ^ (r_[j] & (CPR - 1))) * 8);  // inverse-swizzle (rule #21)
  }
  const int ar = wr + (lane & 15);
  const int br = wc + (lane & 15);
  const int hi = lane >> 4;
  const int nsteps = K / BK;

  auto stage = [&](int buf, int k0) {
    short* Sa = smem + buf * 2 * TILE;
    short* Sb = Sa + TILE;
#pragma unroll
    for (int j = 0; j < NCH; ++j)
      gl2lds16(Ab + (size_t)r_[j] * K + k0 + kk_[j], Sa + (j * 256 + w * 64) * 8);
#pragma unroll
    for (int j = 0; j < NCH; ++j)
      gl2lds16(Bb + (size_t)r_[j] * K + k0 + kk_[j], Sb + (j * 256 + w * 64) * 8);
  };

  stage(0, 0);
  asm volatile("s_waitcnt vmcnt(0)" ::: "memory");
  __syncthreads();
  for (int t = 0; t < nsteps; ++t) {
    const int cur = t & 1;
    if (t + 1 < nsteps) stage(cur ^ 1, (t + 1) * BK);   // prefetch next tile
    const short* As = smem + cur * 2 * TILE;
    const short* Bs = As + TILE;
#pragma unroll
    for (int ks = 0; ks < BK / 32; ++ks) {
      bf16x8 a[4], b[4];
#pragma unroll
      for (int f = 0; f < 4; ++f) {
        int row = ar + f * 16;
        a[f] = *reinterpret_cast<const bf16x8*>(
            &As[row * BK + (((ks * 4 + hi) ^ (row & (CPR - 1))) * 8)]);
      }
#pragma unroll
      for (int f = 0; f < 4; ++f) {
        int row = br + f * 16;
        b[f] = *reinterpret_cast<const bf16x8*>(
            &Bs[row * BK + (((ks * 4 + hi) ^ (row & (CPR - 1))) * 8)]);
      }
#pragma unroll
      for (int fi = 0; fi < 4; ++fi)
#pragma unroll
        for (int fj = 0; fj < 4; ++fj)
          acc[fi][fj] = __builtin_amdgcn_mfma_f32_16x16x32_bf16(a[fi], b[fj], acc[fi][fj], 0, 0, 0);
    }
    asm volatile("s_waitcnt vmcnt(0)" ::: "memory");
    __syncthreads();
  }
  // ---- epilogue: acc -> LDS (bank-conflict-free) -> coalesced 16B stores ----
  short* Cl = smem;                       // 128x128 shorts = 32KB
  const int colbase = wc + (lane & 15);
#pragma unroll
  for (int fj = 0; fj < 4; ++fj) {
    int cl = colbase + fj * 16;
    int n = n0 + cl;
    float bi = bias[n];
    float sc = (MODE == 2) ? scale[n] : 0.f;
#pragma unroll
    for (int fi = 0; fi < 4; ++fi) {
#pragma unroll
      for (int r = 0; r < 4; ++r) {
        int rl = wr + (hi << 2) + fi * 16 + r;
        float v = acc[fi][fj][r] + bi;
        if (MODE == 1) v = fast_gelu(v);
        if (MODE == 2) v *= sc;
        Cl[rl * 128 + (cl ^ (((rl >> 2) & 3) << 4))] = f2b(v);
      }
    }
  }
  __syncthreads();
  const int cs = (lane & 15) * 8;
#pragma unroll
  for (int it = 0; it < 8; ++it) {
    int rl = w * 32 + it * 4 + (lane >> 4);
    s16x8 v = *reinterpret_cast<const s16x8*>(&Cl[rl * 128 + (cs ^ (((rl >> 2) & 3) << 4))]);
    int m = m0 + rl;
    if (MODE == 2) {
      size_t idx = (size_t)m * N + n0 + cs;
      s16x8 hv = *reinterpret_cast<const s16x8*>(&obf[idx]);
      s16x8 o;
#pragma unroll
      for (int j = 0; j < 8; ++j) o[j] = f2b(b2f(hv[j]) + b2f(v[j]));
      *reinterpret_cast<s16x8*>(&obf[idx]) = o;
    } else if (MODE == 3) {
      int bb = m >> 10, t = m & 1023;
      *reinterpret_cast<s16x8*>(&obf[((size_t)(bb * OROWS + 4 + t)) * NFFT_ + n0 + cs]) = v;
    } else {
      *reinterpret_cast<s16x8*>(&obf[(size_t)m * N + n0 + cs]) = v;
    }
  }
}

// ---------------- overlap conv: 128(l)x64(c) tiles, A+B double-buffered -----
// o2[b][l][c] = sum_{k=0..3} sum_n o1p[b][l+1+k][n] * ovb[k][c][n]
// 64 phases (16 k0-steps x 4 ksh); A staged per k0 (dbuf), B per phase (dbuf).
__global__ __launch_bounds__(256) void k_ovgemm(const short* __restrict__ o1p,
                                                const short* __restrict__ ovb,
                                                float* __restrict__ o2) {
  __shared__ __align__(16) short As2[2][136 * 64];
  __shared__ __align__(16) short Bs2[2][64 * 64];
  const int tid = threadIdx.x;
  const int lane = tid & 63, w = tid >> 6;
  const int l0 = blockIdx.x * 128, c0 = blockIdx.y * 64, b = blockIdx.z;
  const int wr = (w >> 1) * 64, wc = (w & 1) * 32;
  f32x4 acc[4][2];
#pragma unroll
  for (int i = 0; i < 4; ++i)
#pragma unroll
    for (int j = 0; j < 2; ++j) acc[i][j] = (f32x4){0.f, 0.f, 0.f, 0.f};

  const short* Ab = o1p + (size_t)b * OROWS * NFFT_;
  const int ar = wr + (lane & 15);
  const int br = wc + (lane & 15);
  const int hi = lane >> 4;
  const int sl_row = lane >> 3;
  const int sl_j   = lane & 7;
  int br_[2], bk_[2];
#pragma unroll
  for (int j = 0; j < 2; ++j) {
    int c = tid + j * 256;
    br_[j] = c >> 3;
    bk_[j] = ((c & 7) ^ (br_[j] & 7)) * 8;
  }

  auto stageA = [&](int buf, int k0) {
    for (int cg = w; cg < 17; cg += 4) {
      int lr = cg * 8 + sl_row;
      int gr = l0 + 1 + lr;
      if (gr > OROWS - 1) gr = OROWS - 1;
      int j = sl_j ^ (lr & 7);
      gl2lds16(Ab + (size_t)gr * NFFT_ + k0 + j * 8, &As2[buf][cg * 512]);
    }
  };
  auto stageB = [&](int buf, int k0, int ksh) {
    const short* Bb = ovb + ((size_t)(ksh * HOP_ + c0)) * NFFT_;
#pragma unroll
    for (int j = 0; j < 2; ++j)
      gl2lds16(Bb + (size_t)br_[j] * NFFT_ + k0 + bk_[j],
               &Bs2[buf][(j * 256 + w * 64) * 8]);
  };

  int ab = 0, bb = 0;
  stageA(0, 0);
  stageB(0, 0, 0);
  asm volatile("s_waitcnt vmcnt(0)" ::: "memory");
  __syncthreads();
  for (int t = 0; t < 64; ++t) {            // 16 k0-steps x 4 ksh
    const int ksh = t & 3;
    const int nt = t + 1;
    if (nt < 64) {
      int nk0 = (nt >> 2) << 6;
      if ((nt & 3) == 0) stageA(ab ^ 1, nk0);
      stageB(bb ^ 1, nk0, nt & 3);
    }
    const short* As = As2[ab];
    const short* Bs = Bs2[bb];
#pragma unroll
    for (int ks = 0; ks < 2; ++ks) {
      bf16x8 a[4], bfr[2];
#pragma unroll
      for (int f = 0; f < 4; ++f) {
        int row = ar + f * 16 + ksh;
        a[f] = *reinterpret_cast<const bf16x8*>(&As[row * 64 + (((ks * 4 + hi) ^ (row & 7)) * 8)]);
      }
#pragma unroll
      for (int f = 0; f < 2; ++f) {
        int row = br + f * 16;
        bfr[f] = *reinterpret_cast<const bf16x8*>(&Bs[row * 64 + (((ks * 4 + hi) ^ (row & 7)) * 8)]);
      }
#pragma unroll
      for (int fi = 0; fi < 4; ++fi)
#pragma unroll
        for (int fj = 0; fj < 2; ++fj)
          acc[fi][fj] = __builtin_amdgcn_mfma_f32_16x16x32_bf16(a[fi], bfr[fj], acc[fi][fj], 0, 0, 0);
    }
    asm volatile("s_waitcnt vmcnt(0)" ::: "memory");
    __syncthreads();
    bb ^= 1;
    if (ksh == 3) ab ^= 1;
  }
  const int lb = l0 + wr + (hi << 2);
  const int cb = c0 + wc + (lane & 15);
#pragma unroll
  for (int fj = 0; fj < 2; ++fj) {
    int c = cb + fj * 16;
#pragma unroll
    for (int fi = 0; fi < 4; ++fi) {
#pragma unroll
      for (int r = 0; r < 4; ++r) {
        int l = lb + fi * 16 + r;
        if (l < L_) o2[((size_t)b * L_ + l) * HOP_ + c] = acc[fi][fj][r];
      }
    }
  }
}

// ---------------- final gather-sum over o2[b][l][c] -------------------------
__global__ __launch_bounds__(256) void k_oadd(const float* __restrict__ o2,
                                              float* __restrict__ out) {
  int b = blockIdx.x;
  int t = blockIdx.y * 256 + threadIdx.x;
  int m = t + 2;
  float s = 0.f;
  for (int c = 0; c < HOP_; ++c) {
    s += o2[((size_t)b * L_ + m) * HOP_ + c];
    m -= 4;
    if (m < 0) m += L_;
  }
  out[b * T_ + t] = s;
}

extern "C" void kernel_launch(void* const* d_in, const int* in_sizes, int n_in,
                              void* d_out, int out_size, void* d_ws, size_t ws_size,
                              hipStream_t stream) {
  const float* x      = (const float*)d_in[0];
  const float* in_w   = (const float*)d_in[1];
  const float* in_b   = (const float*)d_in[2];
  const float* norm_g = (const float*)d_in[3];
  const float* norm_b = (const float*)d_in[4];
  const float* dw_w   = (const float*)d_in[5];
  const float* dw_b   = (const float*)d_in[6];
  const float* ln_g   = (const float*)d_in[7];
  const float* ln_b   = (const float*)d_in[8];
  const float* pw1_w  = (const float*)d_in[9];
  const float* pw1_b  = (const float*)d_in[10];
  const float* pw2_w  = (const float*)d_in[11];
  const float* pw2_b  = (const float*)d_in[12];
  const float* ls     = (const float*)d_in[13];
  const float* normLg = (const float*)d_in[14];
  const float* normLb = (const float*)d_in[15];
  const float* out_w  = (const float*)d_in[16];
  const float* out_b  = (const float*)d_in[17];
  const float* ov_w   = (const float*)d_in[18];
  float* out = (float*)d_out;

  char* p = (char*)d_ws;
  short* hb   = (short*)p; p += (size_t)BT * CH_ * 2;        // 16.78 MB
  short* yb   = (short*)p; p += (size_t)BT * CH_ * 2;        // 16.78 MB
  short* zb   = (short*)p; p += (size_t)BT * HCH_ * 2;       // 50.33 MB
  short* pw1b = (short*)p; p += (size_t)NL_ * HCH_ * CH_ * 2;
  short* pw2b = (short*)p; p += (size_t)NL_ * CH_ * HCH_ * 2;
  short* owb  = (short*)p; p += (size_t)NFFT_ * CH_ * 2;
  short* ovb  = (short*)p; p += (size_t)4 * HOP_ * NFFT_ * 2;
  float* dwt  = (float*)p; p += (size_t)NL_ * 7 * CH_ * 4;
  short* xim  = zb;                        // alias: zb not yet used
  short* wib  = zb + (size_t)BT * KIN;     // fits (23.6 MB < 50.3 MB)
  short* hbL  = yb;                        // alias: yb dead when final LN runs
  short* o1p  = zb;                        // alias: zb dead after layer loop
  float* o2   = (float*)hb;                // spans hb + start of yb; both dead

  k_cvt4<<<4096, 256, 0, stream>>>(pw1_w, pw1b, NL_ * HCH_ * CH_ / 4);
  k_cvt4<<<4096, 256, 0, stream>>>(pw2_w, pw2b, NL_ * CH_ * HCH_ / 4);
  k_cvt4<<<512, 256, 0, stream>>>(out_w, owb, NFFT_ * CH_ / 4);
  k_cvt_ov<<<1024, 256, 0, stream>>>(ov_w, ovb);
  k_cvt_inw<<<1408, 256, 0, stream>>>(in_w, wib);
  k_cvt_dwt<<<112, 256, 0, stream>>>(dw_w, dwt);
  k_im2col<<<8192, 256, 0, stream>>>(x, xim);

  k_mgemm<0, 64><<<512, 256, 0, stream>>>(xim, wib, in_b, nullptr, hb, CH_, KIN);
  k_lnb<<<BT, 256, 0, stream>>>(hb, hb, norm_g, norm_b);
  for (int l = 0; l < NL_; ++l) {
    k_dwln<<<dim3(B_, T_ / 32), 256, 0, stream>>>(
        hb, dwt + (size_t)l * 7 * CH_, dw_b + l * CH_,
        ln_g + l * CH_, ln_b + l * CH_, yb);
    k_mgemm<1, 32><<<1536, 256, 0, stream>>>(
        yb, pw1b + (size_t)l * HCH_ * CH_, pw1_b + l * HCH_, nullptr, zb,
        HCH_, CH_);
    k_mgemm<2, 64><<<512, 256, 0, stream>>>(
        zb, pw2b + (size_t)l * CH_ * HCH_, pw2_b + l * CH_, ls + l * CH_, hb,
        CH_, HCH_);
  }
  k_lnb<<<BT, 256, 0, stream>>>(hb, hbL, normLg, normLb);
  k_mgemm<3, 32><<<1024, 256, 0, stream>>>(hbL, owb, out_b, nullptr, o1p, NFFT_, CH_);
  k_zeropad<<<512, 256, 0, stream>>>(o1p);
  k_ovgemm<<<dim3(9, 4, 16), 256, 0, stream>>>(o1p, ovb, o2);
  k_oadd<<<dim3(B_, 4), 256, 0, stream>>>(o2, out);
}

// Round 12
// 900.931 us; speedup vs baseline: 1.1651x; 1.0066x over previous
//
#include <hip/hip_runtime.h>

#define B_    16
#define CIN   100
#define T_    1024
#define CH_   512
#define HCH_  1536
#define NL_   8
#define NFFT_ 1024
#define HOP_  256
#define BT    (B_ * T_)
#define L_    1027
#define OROWS 1032   // padded o1 rows per batch: [4 zero | 1024 data | 4 zero]
#define KIN   704    // im2col K for in-conv (100*7 -> pad 704)

typedef __bf16 bf16x8 __attribute__((ext_vector_type(8)));
typedef float f32x4 __attribute__((ext_vector_type(4)));
typedef short s16x8 __attribute__((ext_vector_type(8)));
typedef short s16x4 __attribute__((ext_vector_type(4)));

__device__ __forceinline__ short f2b(float f) {
  unsigned u = __float_as_uint(f);
  u += 0x7fffu + ((u >> 16) & 1u);
  return (short)(u >> 16);
}
__device__ __forceinline__ float b2f(short s) {
  return __uint_as_float(((unsigned)(unsigned short)s) << 16);
}

// fast tanh-GELU (odd-symmetric, overflow-safe); |err| vs exact-erf ~1.5e-3
__device__ __forceinline__ float fast_gelu(float x) {
  float ax = fabsf(x);
  float z = 0.7978845608f * ax * (1.f + 0.044715f * ax * ax);
  float e = __expf(-2.f * z);
  float th = 1.f - 2.f * e * __builtin_amdgcn_rcpf(1.f + e);  // tanh(z) >= 0
  float g = copysignf(th, x);
  return 0.5f * x * (1.f + g);
}

__device__ __forceinline__ void gl2lds16(const void* g, void* l) {
  __builtin_amdgcn_global_load_lds(
      (__attribute__((address_space(1))) void*)g,
      (__attribute__((address_space(3))) void*)l, 16, 0, 0);
}

// ---------------- weight fp32 -> bf16, vectorized (n % 4 == 0) --------------
__global__ __launch_bounds__(256) void k_cvt4(const float* __restrict__ s,
                                              short* __restrict__ d, int n4) {
  for (int i = blockIdx.x * 256 + threadIdx.x; i < n4; i += gridDim.x * 256) {
    f32x4 v = *reinterpret_cast<const f32x4*>(&s[i * 4]);
    s16x4 o = {f2b(v[0]), f2b(v[1]), f2b(v[2]), f2b(v[3])};
    *reinterpret_cast<s16x4*>(&d[i * 4]) = o;
  }
}

// ov_w[c][n][k] -> ovb[k][c][n] bf16 (coalesced read 16B, 4 coalesced planes)
__global__ __launch_bounds__(256) void k_cvt_ov(const float* __restrict__ w,
                                                short* __restrict__ d) {
  const int n = HOP_ * NFFT_;   // (c,n) pairs
  for (int i = blockIdx.x * 256 + threadIdx.x; i < n; i += gridDim.x * 256) {
    f32x4 v = *reinterpret_cast<const f32x4*>(&w[(size_t)i * 4]);
#pragma unroll
    for (int k = 0; k < 4; ++k) d[(size_t)k * n + i] = f2b(v[k]);
  }
}

// in_w[c][ci][k] (700 contiguous per c) -> wib[c][704] bf16, pad 0
__global__ __launch_bounds__(256) void k_cvt_inw(const float* __restrict__ w,
                                                 short* __restrict__ d) {
  const int n = CH_ * KIN;
  for (int i = blockIdx.x * 256 + threadIdx.x; i < n; i += gridDim.x * 256) {
    int c = i / KIN, e = i - c * KIN;
    d[i] = (e < 700) ? f2b(w[c * 700 + e]) : (short)0;
  }
}

// dw_w [NL][512][7] fp32 -> dwt [NL][7][512] fp32
__global__ __launch_bounds__(256) void k_cvt_dwt(const float* __restrict__ w,
                                                 float* __restrict__ d) {
  const int n = NL_ * 7 * CH_;
  for (int i = blockIdx.x * 256 + threadIdx.x; i < n; i += gridDim.x * 256) {
    int l = i / (7 * CH_), r = i - l * 7 * CH_;
    int k = r >> 9, c = r & 511;
    d[i] = w[((size_t)l * CH_ + c) * 7 + k];
  }
}

// x[b][ci][t] fp32 -> xim[b*T+t][ci*7+k] = x[b,ci,t+k-3] bf16 (0 pad)
__global__ __launch_bounds__(256) void k_im2col(const float* __restrict__ x,
                                                short* __restrict__ xim) {
  const int total = BT * KIN;
  for (int i = blockIdx.x * 256 + threadIdx.x; i < total; i += gridDim.x * 256) {
    int m = i / KIN, e = i - m * KIN;
    int b = m >> 10, t = m & 1023;
    int ci = e / 7, k = e - ci * 7;
    int tt = t + k - 3;
    float v = (e < 700 && tt >= 0 && tt < T_) ? x[((b * CIN + ci) << 10) + tt] : 0.f;
    xim[i] = f2b(v);
  }
}

// zero the 4+4 pad rows of o1p per batch
__global__ __launch_bounds__(256) void k_zeropad(short* __restrict__ o1p) {
  int i = blockIdx.x * 256 + threadIdx.x;  // 131072
  int b = i >> 13;
  int r8 = (i >> 10) & 7;
  int nn = i & 1023;
  int row = r8 < 4 ? r8 : (OROWS - 8 + r8);
  o1p[((size_t)b * OROWS + row) * NFFT_ + nn] = 0;
}

// ---------------- layernorm bf16 -> bf16 (row of 512) -----------------------
__global__ __launch_bounds__(256) void k_lnb(const short* __restrict__ in,
                                             short* __restrict__ outp,
                                             const float* __restrict__ g,
                                             const float* __restrict__ bta) {
  int row = blockIdx.x, tid = threadIdx.x;
  unsigned u = *reinterpret_cast<const unsigned*>(&in[(size_t)row * CH_ + tid * 2]);
  float v0 = __uint_as_float(u << 16);
  float v1 = __uint_as_float(u & 0xffff0000u);
  float s = v0 + v1, q = v0 * v0 + v1 * v1;
#pragma unroll
  for (int o = 32; o > 0; o >>= 1) { s += __shfl_down(s, o); q += __shfl_down(q, o); }
  __shared__ float sh[8];
  int wid = tid >> 6, lane = tid & 63;
  if (lane == 0) { sh[wid] = s; sh[wid + 4] = q; }
  __syncthreads();
  float S = sh[0] + sh[1] + sh[2] + sh[3];
  float Q = sh[4] + sh[5] + sh[6] + sh[7];
  float mu  = S * (1.f / 512.f);
  float var = Q * (1.f / 512.f) - mu * mu;
  float r = rsqrtf(var + 1e-5f);
  float x0 = (v0 - mu) * r * g[tid * 2]     + bta[tid * 2];
  float x1 = (v1 - mu) * r * g[tid * 2 + 1] + bta[tid * 2 + 1];
  unsigned o = ((unsigned)(unsigned short)f2b(x0)) |
               (((unsigned)(unsigned short)f2b(x1)) << 16);
  *reinterpret_cast<unsigned*>(&outp[(size_t)row * CH_ + tid * 2]) = o;
}

// ---------------- fused depthwise 7-tap + LN, bf16, wave-per-row ------------
__global__ __launch_bounds__(256) void k_dwln(const short* __restrict__ h,
                                              const float* __restrict__ dwt,  // [7][512]
                                              const float* __restrict__ dwb,
                                              const float* __restrict__ g,
                                              const float* __restrict__ bta,
                                              short* __restrict__ yb) {
  int b = blockIdx.x, t0 = blockIdx.y * 32;
  int tid = threadIdx.x, lane = tid & 63, w = tid >> 6;
  __shared__ short hs[38][512];
  for (int e = tid; e < 38 * 64; e += 256) {
    int row = e >> 6, seg = (e & 63) << 3;
    int t = t0 - 3 + row;
    s16x8 v = {};
    if (t >= 0 && t < T_)
      v = *reinterpret_cast<const s16x8*>(&h[((size_t)((b << 10) + t)) * CH_ + seg]);
    *reinterpret_cast<s16x8*>(&hs[row][seg]) = v;
  }
  const int c0 = lane << 3;
  float wk[7][8];
#pragma unroll
  for (int k = 0; k < 7; ++k) {
    f32x4 lo = *reinterpret_cast<const f32x4*>(&dwt[k * CH_ + c0]);
    f32x4 hi = *reinterpret_cast<const f32x4*>(&dwt[k * CH_ + c0 + 4]);
#pragma unroll
    for (int j = 0; j < 4; ++j) { wk[k][j] = lo[j]; wk[k][j + 4] = hi[j]; }
  }
  float bb[8], gg[8], be[8];
  {
    f32x4 a = *reinterpret_cast<const f32x4*>(&dwb[c0]);
    f32x4 b4 = *reinterpret_cast<const f32x4*>(&dwb[c0 + 4]);
    f32x4 c = *reinterpret_cast<const f32x4*>(&g[c0]);
    f32x4 d = *reinterpret_cast<const f32x4*>(&g[c0 + 4]);
    f32x4 e = *reinterpret_cast<const f32x4*>(&bta[c0]);
    f32x4 f = *reinterpret_cast<const f32x4*>(&bta[c0 + 4]);
#pragma unroll
    for (int j = 0; j < 4; ++j) {
      bb[j] = a[j]; bb[j + 4] = b4[j];
      gg[j] = c[j]; gg[j + 4] = d[j];
      be[j] = e[j]; be[j + 4] = f[j];
    }
  }
  __syncthreads();
#pragma unroll
  for (int i = 0; i < 8; ++i) {
    int r = w * 8 + i;
    float acc[8];
#pragma unroll
    for (int j = 0; j < 8; ++j) acc[j] = bb[j];
#pragma unroll
    for (int k = 0; k < 7; ++k) {
      s16x8 hv = *reinterpret_cast<const s16x8*>(&hs[r + k][c0]);
#pragma unroll
      for (int j = 0; j < 8; ++j) acc[j] += b2f(hv[j]) * wk[k][j];
    }
    float s = 0.f, q = 0.f;
#pragma unroll
    for (int j = 0; j < 8; ++j) { s += acc[j]; q += acc[j] * acc[j]; }
#pragma unroll
    for (int o = 32; o > 0; o >>= 1) { s += __shfl_xor(s, o); q += __shfl_xor(q, o); }
    float mu  = s * (1.f / 512.f);
    float var = q * (1.f / 512.f) - mu * mu;
    float rr = rsqrtf(var + 1e-5f);
    s16x8 ov;
#pragma unroll
    for (int j = 0; j < 8; ++j) ov[j] = f2b((acc[j] - mu) * rr * gg[j] + be[j]);
    *reinterpret_cast<s16x8*>(&yb[((size_t)((b << 10) + t0 + r)) * CH_ + c0]) = ov;
  }
}

// ---------------- bf16 MFMA GEMM: C[m,n] = sum_k A[m,k]*Bw[n,k] -------------
// 128x128 tile, 4 waves, 2-phase double-buffered pipeline, BK parameterized.
// BK=32 -> 32KB LDS (~5 blocks/CU); swizzle uses (row>>1)&3 (rows span only
// 16 banks, so the XOR must vary per bank-half pair -> 2-way max = free).
// BK=64 -> 64KB LDS; swizzle row&7 (row spans all 32 banks). [rule #21: same
// involution applied on inverse-swizzled global source and LDS read]
// MODE 0: obf = bf16(acc+bias)
// MODE 1: obf = bf16(gelu(acc+bias))
// MODE 2: obf[m][n] = bf16(obf + bf16((acc+bias)*scale))   (residual RMW)
// MODE 3: obf = bf16(acc+bias) at padded o1 rows (b*OROWS+4+t), stride NFFT
template <int MODE, int BK>
__global__ __launch_bounds__(256) void k_mgemm(const short* __restrict__ A,
                                               const short* __restrict__ Bw,
                                               const float* __restrict__ bias,
                                               const float* __restrict__ scale,
                                               short* __restrict__ obf,
                                               int N, int K) {
  constexpr int CPR  = BK / 8;            // 16B chunks per row
  constexpr int NCH  = BK / 16;           // staging chunks per thread (A or B)
  constexpr int TILE = 128 * BK;          // shorts per A (or B) buf
  constexpr int SSH  = (BK == 32) ? 1 : 0;  // swizzle row shift
  constexpr int SMEM = (4 * TILE > 16384) ? 4 * TILE : 16384;
  __shared__ __align__(16) short smem[SMEM];
  const int tid = threadIdx.x;
  const int lane = tid & 63, w = tid >> 6;
  const int id = blockIdx.x;
  const int ny = N >> 7;
  const int g8 = id >> 3;
  const int gq = g8 / ny;
  const int mt = (id & 7) + (gq << 3);
  const int nt_ = g8 - gq * ny;
  const int m0 = mt << 7, n0 = nt_ << 7;
  const int wr = (w >> 1) * 64, wc = (w & 1) * 64;
  f32x4 acc[4][4];
#pragma unroll
  for (int i = 0; i < 4; ++i)
#pragma unroll
    for (int j = 0; j < 4; ++j) acc[i][j] = (f32x4){0.f, 0.f, 0.f, 0.f};

  const short* Ab = A + (size_t)m0 * K;
  const short* Bb = Bw + (size_t)n0 * K;
  int r_[NCH], kk_[NCH];
#pragma unroll
  for (int j = 0; j < NCH; ++j) {
    int c = tid + j * 256;
    r_[j] = c / CPR;
    kk_[j] = (((c % CPR) ^ ((r_[j] >> SSH) & (CPR - 1))) * 8);  // inv-swizzle
  }
  const int ar = wr + (lane & 15);
  const int br = wc + (lane & 15);
  const int hi = lane >> 4;
  const int nsteps = K / BK;

  auto stage = [&](int buf, int k0) {
    short* Sa = smem + buf * 2 * TILE;
    short* Sb = Sa + TILE;
#pragma unroll
    for (int j = 0; j < NCH; ++j)
      gl2lds16(Ab + (size_t)r_[j] * K + k0 + kk_[j], Sa + (j * 256 + w * 64) * 8);
#pragma unroll
    for (int j = 0; j < NCH; ++j)
      gl2lds16(Bb + (size_t)r_[j] * K + k0 + kk_[j], Sb + (j * 256 + w * 64) * 8);
  };

  stage(0, 0);
  asm volatile("s_waitcnt vmcnt(0)" ::: "memory");
  __syncthreads();
  for (int t = 0; t < nsteps; ++t) {
    const int cur = t & 1;
    if (t + 1 < nsteps) stage(cur ^ 1, (t + 1) * BK);   // prefetch next tile
    const short* As = smem + cur * 2 * TILE;
    const short* Bs = As + TILE;
#pragma unroll
    for (int ks = 0; ks < BK / 32; ++ks) {
      bf16x8 a[4], b[4];
#pragma unroll
      for (int f = 0; f < 4; ++f) {
        int row = ar + f * 16;
        a[f] = *reinterpret_cast<const bf16x8*>(
            &As[row * BK + (((ks * 4 + hi) ^ ((row >> SSH) & (CPR - 1))) * 8)]);
      }
#pragma unroll
      for (int f = 0; f < 4; ++f) {
        int row = br + f * 16;
        b[f] = *reinterpret_cast<const bf16x8*>(
            &Bs[row * BK + (((ks * 4 + hi) ^ ((row >> SSH) & (CPR - 1))) * 8)]);
      }
#pragma unroll
      for (int fi = 0; fi < 4; ++fi)
#pragma unroll
        for (int fj = 0; fj < 4; ++fj)
          acc[fi][fj] = __builtin_amdgcn_mfma_f32_16x16x32_bf16(a[fi], b[fj], acc[fi][fj], 0, 0, 0);
    }
    asm volatile("s_waitcnt vmcnt(0)" ::: "memory");
    __syncthreads();
  }
  // ---- epilogue: acc -> LDS (bank-conflict-free) -> coalesced 16B stores ----
  short* Cl = smem;                       // 128x128 shorts = 32KB
  const int colbase = wc + (lane & 15);
#pragma unroll
  for (int fj = 0; fj < 4; ++fj) {
    int cl = colbase + fj * 16;
    int n = n0 + cl;
    float bi = bias[n];
    float sc = (MODE == 2) ? scale[n] : 0.f;
#pragma unroll
    for (int fi = 0; fi < 4; ++fi) {
#pragma unroll
      for (int r = 0; r < 4; ++r) {
        int rl = wr + (hi << 2) + fi * 16 + r;
        float v = acc[fi][fj][r] + bi;
        if (MODE == 1) v = fast_gelu(v);
        if (MODE == 2) v *= sc;
        Cl[rl * 128 + (cl ^ (((rl >> 2) & 3) << 4))] = f2b(v);
      }
    }
  }
  __syncthreads();
  const int cs = (lane & 15) * 8;
#pragma unroll
  for (int it = 0; it < 8; ++it) {
    int rl = w * 32 + it * 4 + (lane >> 4);
    s16x8 v = *reinterpret_cast<const s16x8*>(&Cl[rl * 128 + (cs ^ (((rl >> 2) & 3) << 4))]);
    int m = m0 + rl;
    if (MODE == 2) {
      size_t idx = (size_t)m * N + n0 + cs;
      s16x8 hv = *reinterpret_cast<const s16x8*>(&obf[idx]);
      s16x8 o;
#pragma unroll
      for (int j = 0; j < 8; ++j) o[j] = f2b(b2f(hv[j]) + b2f(v[j]));
      *reinterpret_cast<s16x8*>(&obf[idx]) = o;
    } else if (MODE == 3) {
      int bb = m >> 10, t = m & 1023;
      *reinterpret_cast<s16x8*>(&obf[((size_t)(bb * OROWS + 4 + t)) * NFFT_ + n0 + cs]) = v;
    } else {
      *reinterpret_cast<s16x8*>(&obf[(size_t)m * N + n0 + cs]) = v;
    }
  }
}

// ---------------- overlap conv: 128(l)x64(c) tiles, A+B double-buffered -----
// o2[b][l][c] = sum_{k=0..3} sum_n o1p[b][l+1+k][n] * ovb[k][c][n]
// 1D grid 576, XCD-grouped: the 4 c-tiles of one (l,b) A-panel share id%8
// -> same XCD L2 -> A fetched once per panel.
__global__ __launch_bounds__(256) void k_ovgemm(const short* __restrict__ o1p,
                                                const short* __restrict__ ovb,
                                                float* __restrict__ o2) {
  __shared__ __align__(16) short As2[2][136 * 64];
  __shared__ __align__(16) short Bs2[2][64 * 64];
  const int tid = threadIdx.x;
  const int lane = tid & 63, w = tid >> 6;
  const int id = blockIdx.x;
  const int xcd = id & 7, rr = id >> 3;
  const int ct = rr & 3, phi = rr >> 2;       // phi in 0..17
  const int pp = xcd * 18 + phi;              // pair in 0..143
  const int l0 = (pp % 9) * 128, c0 = ct * 64, b = pp / 9;
  const int wr = (w >> 1) * 64, wc = (w & 1) * 32;
  f32x4 acc[4][2];
#pragma unroll
  for (int i = 0; i < 4; ++i)
#pragma unroll
    for (int j = 0; j < 2; ++j) acc[i][j] = (f32x4){0.f, 0.f, 0.f, 0.f};

  const short* Ab = o1p + (size_t)b * OROWS * NFFT_;
  const int ar = wr + (lane & 15);
  const int br = wc + (lane & 15);
  const int hi = lane >> 4;
  const int sl_row = lane >> 3;
  const int sl_j   = lane & 7;
  int br_[2], bk_[2];
#pragma unroll
  for (int j = 0; j < 2; ++j) {
    int c = tid + j * 256;
    br_[j] = c >> 3;
    bk_[j] = ((c & 7) ^ (br_[j] & 7)) * 8;
  }

  auto stageA = [&](int buf, int k0) {
    for (int cg = w; cg < 17; cg += 4) {
      int lr = cg * 8 + sl_row;
      int gr = l0 + 1 + lr;
      if (gr > OROWS - 1) gr = OROWS - 1;
      int j = sl_j ^ (lr & 7);
      gl2lds16(Ab + (size_t)gr * NFFT_ + k0 + j * 8, &As2[buf][cg * 512]);
    }
  };
  auto stageB = [&](int buf, int k0, int ksh) {
    const short* Bb = ovb + ((size_t)(ksh * HOP_ + c0)) * NFFT_;
#pragma unroll
    for (int j = 0; j < 2; ++j)
      gl2lds16(Bb + (size_t)br_[j] * NFFT_ + k0 + bk_[j],
               &Bs2[buf][(j * 256 + w * 64) * 8]);
  };

  int ab = 0, bb = 0;
  stageA(0, 0);
  stageB(0, 0, 0);
  asm volatile("s_waitcnt vmcnt(0)" ::: "memory");
  __syncthreads();
  for (int t = 0; t < 64; ++t) {            // 16 k0-steps x 4 ksh
    const int ksh = t & 3;
    const int nt = t + 1;
    if (nt < 64) {
      int nk0 = (nt >> 2) << 6;
      if ((nt & 3) == 0) stageA(ab ^ 1, nk0);
      stageB(bb ^ 1, nk0, nt & 3);
    }
    const short* As = As2[ab];
    const short* Bs = Bs2[bb];
#pragma unroll
    for (int ks = 0; ks < 2; ++ks) {
      bf16x8 a[4], bfr[2];
#pragma unroll
      for (int f = 0; f < 4; ++f) {
        int row = ar + f * 16 + ksh;
        a[f] = *reinterpret_cast<const bf16x8*>(&As[row * 64 + (((ks * 4 + hi) ^ (row & 7)) * 8)]);
      }
#pragma unroll
      for (int f = 0; f < 2; ++f) {
        int row = br + f * 16;
        bfr[f] = *reinterpret_cast<const bf16x8*>(&Bs[row * 64 + (((ks * 4 + hi) ^ (row & 7)) * 8)]);
      }
#pragma unroll
      for (int fi = 0; fi < 4; ++fi)
#pragma unroll
        for (int fj = 0; fj < 2; ++fj)
          acc[fi][fj] = __builtin_amdgcn_mfma_f32_16x16x32_bf16(a[fi], bfr[fj], acc[fi][fj], 0, 0, 0);
    }
    asm volatile("s_waitcnt vmcnt(0)" ::: "memory");
    __syncthreads();
    bb ^= 1;
    if (ksh == 3) ab ^= 1;
  }
  const int lb = l0 + wr + (hi << 2);
  const int cb = c0 + wc + (lane & 15);
#pragma unroll
  for (int fj = 0; fj < 2; ++fj) {
    int c = cb + fj * 16;
#pragma unroll
    for (int fi = 0; fi < 4; ++fi) {
#pragma unroll
      for (int r = 0; r < 4; ++r) {
        int l = lb + fi * 16 + r;
        if (l < L_) o2[((size_t)b * L_ + l) * HOP_ + c] = acc[fi][fj][r];
      }
    }
  }
}

// ---------------- final gather-sum over o2[b][l][c] -------------------------
__global__ __launch_bounds__(256) void k_oadd(const float* __restrict__ o2,
                                              float* __restrict__ out) {
  int b = blockIdx.x;
  int t = blockIdx.y * 256 + threadIdx.x;
  int m = t + 2;
  float s = 0.f;
  for (int c = 0; c < HOP_; ++c) {
    s += o2[((size_t)b * L_ + m) * HOP_ + c];
    m -= 4;
    if (m < 0) m += L_;
  }
  out[b * T_ + t] = s;
}

extern "C" void kernel_launch(void* const* d_in, const int* in_sizes, int n_in,
                              void* d_out, int out_size, void* d_ws, size_t ws_size,
                              hipStream_t stream) {
  const float* x      = (const float*)d_in[0];
  const float* in_w   = (const float*)d_in[1];
  const float* in_b   = (const float*)d_in[2];
  const float* norm_g = (const float*)d_in[3];
  const float* norm_b = (const float*)d_in[4];
  const float* dw_w   = (const float*)d_in[5];
  const float* dw_b   = (const float*)d_in[6];
  const float* ln_g   = (const float*)d_in[7];
  const float* ln_b   = (const float*)d_in[8];
  const float* pw1_w  = (const float*)d_in[9];
  const float* pw1_b  = (const float*)d_in[10];
  const float* pw2_w  = (const float*)d_in[11];
  const float* pw2_b  = (const float*)d_in[12];
  const float* ls     = (const float*)d_in[13];
  const float* normLg = (const float*)d_in[14];
  const float* normLb = (const float*)d_in[15];
  const float* out_w  = (const float*)d_in[16];
  const float* out_b  = (const float*)d_in[17];
  const float* ov_w   = (const float*)d_in[18];
  float* out = (float*)d_out;

  char* p = (char*)d_ws;
  short* hb   = (short*)p; p += (size_t)BT * CH_ * 2;        // 16.78 MB
  short* yb   = (short*)p; p += (size_t)BT * CH_ * 2;        // 16.78 MB
  short* zb   = (short*)p; p += (size_t)BT * HCH_ * 2;       // 50.33 MB
  short* pw1b = (short*)p; p += (size_t)NL_ * HCH_ * CH_ * 2;
  short* pw2b = (short*)p; p += (size_t)NL_ * CH_ * HCH_ * 2;
  short* owb  = (short*)p; p += (size_t)NFFT_ * CH_ * 2;
  short* ovb  = (short*)p; p += (size_t)4 * HOP_ * NFFT_ * 2;
  float* dwt  = (float*)p; p += (size_t)NL_ * 7 * CH_ * 4;
  short* xim  = zb;                        // alias: zb not yet used
  short* wib  = zb + (size_t)BT * KIN;     // fits (23.6 MB < 50.3 MB)
  short* hbL  = yb;                        // alias: yb dead when final LN runs
  short* o1p  = zb;                        // alias: zb dead after layer loop
  float* o2   = (float*)hb;                // spans hb + start of yb; both dead

  k_cvt4<<<4096, 256, 0, stream>>>(pw1_w, pw1b, NL_ * HCH_ * CH_ / 4);
  k_cvt4<<<4096, 256, 0, stream>>>(pw2_w, pw2b, NL_ * CH_ * HCH_ / 4);
  k_cvt4<<<512, 256, 0, stream>>>(out_w, owb, NFFT_ * CH_ / 4);
  k_cvt_ov<<<1024, 256, 0, stream>>>(ov_w, ovb);
  k_cvt_inw<<<1408, 256, 0, stream>>>(in_w, wib);
  k_cvt_dwt<<<112, 256, 0, stream>>>(dw_w, dwt);
  k_im2col<<<8192, 256, 0, stream>>>(x, xim);

  k_mgemm<0, 64><<<512, 256, 0, stream>>>(xim, wib, in_b, nullptr, hb, CH_, KIN);
  k_lnb<<<BT, 256, 0, stream>>>(hb, hb, norm_g, norm_b);
  for (int l = 0; l < NL_; ++l) {
    k_dwln<<<dim3(B_, T_ / 32), 256, 0, stream>>>(
        hb, dwt + (size_t)l * 7 * CH_, dw_b + l * CH_,
        ln_g + l * CH_, ln_b + l * CH_, yb);
    k_mgemm<1, 32><<<1536, 256, 0, stream>>>(
        yb, pw1b + (size_t)l * HCH_ * CH_, pw1_b + l * HCH_, nullptr, zb,
        HCH_, CH_);
    k_mgemm<2, 64><<<512, 256, 0, stream>>>(
        zb, pw2b + (size_t)l * CH_ * HCH_, pw2_b + l * CH_, ls + l * CH_, hb,
        CH_, HCH_);
  }
  k_lnb<<<BT, 256, 0, stream>>>(hb, hbL, normLg, normLb);
  k_mgemm<3, 32><<<1024, 256, 0, stream>>>(hbL, owb, out_b, nullptr, o1p, NFFT_, CH_);
  k_zeropad<<<512, 256, 0, stream>>>(o1p);
  k_ovgemm<<<576, 256, 0, stream>>>(o1p, ovb, o2);
  k_oadd<<<dim3(B_, 4), 256, 0, stream>>>(o2, out);
}

// Round 13
// 867.306 us; speedup vs baseline: 1.2103x; 1.0388x over previous
//
#include <hip/hip_runtime.h>

#define B_    16
#define CIN   100
#define T_    1024
#define CH_   512
#define HCH_  1536
#define NL_   8
#define NFFT_ 1024
#define HOP_  256
#define BT    (B_ * T_)
#define L_    1027
#define OROWS 1032   // padded o1 rows per batch: [4 zero | 1024 data | 4 zero]
#define KIN   704    // im2col K for in-conv (100*7 -> pad 704)

typedef __bf16 bf16x8 __attribute__((ext_vector_type(8)));
typedef float f32x4 __attribute__((ext_vector_type(4)));
typedef short s16x8 __attribute__((ext_vector_type(8)));
typedef short s16x4 __attribute__((ext_vector_type(4)));

__device__ __forceinline__ short f2b(float f) {
  unsigned u = __float_as_uint(f);
  u += 0x7fffu + ((u >> 16) & 1u);
  return (short)(u >> 16);
}
__device__ __forceinline__ float b2f(short s) {
  return __uint_as_float(((unsigned)(unsigned short)s) << 16);
}

// fast tanh-GELU (odd-symmetric, overflow-safe); |err| vs exact-erf ~1.5e-3
__device__ __forceinline__ float fast_gelu(float x) {
  float ax = fabsf(x);
  float z = 0.7978845608f * ax * (1.f + 0.044715f * ax * ax);
  float e = __expf(-2.f * z);
  float th = 1.f - 2.f * e * __builtin_amdgcn_rcpf(1.f + e);  // tanh(z) >= 0
  float g = copysignf(th, x);
  return 0.5f * x * (1.f + g);
}

__device__ __forceinline__ void gl2lds16(const void* g, void* l) {
  __builtin_amdgcn_global_load_lds(
      (__attribute__((address_space(1))) void*)g,
      (__attribute__((address_space(3))) void*)l, 16, 0, 0);
}

// ---------------- weight fp32 -> bf16, vectorized (n % 4 == 0) --------------
__global__ __launch_bounds__(256) void k_cvt4(const float* __restrict__ s,
                                              short* __restrict__ d, int n4) {
  for (int i = blockIdx.x * 256 + threadIdx.x; i < n4; i += gridDim.x * 256) {
    f32x4 v = *reinterpret_cast<const f32x4*>(&s[i * 4]);
    s16x4 o = {f2b(v[0]), f2b(v[1]), f2b(v[2]), f2b(v[3])};
    *reinterpret_cast<s16x4*>(&d[i * 4]) = o;
  }
}

// ov_w[c][n][k] -> ovb[k][c][n] bf16 (coalesced read 16B, 4 coalesced planes)
__global__ __launch_bounds__(256) void k_cvt_ov(const float* __restrict__ w,
                                                short* __restrict__ d) {
  const int n = HOP_ * NFFT_;   // (c,n) pairs
  for (int i = blockIdx.x * 256 + threadIdx.x; i < n; i += gridDim.x * 256) {
    f32x4 v = *reinterpret_cast<const f32x4*>(&w[(size_t)i * 4]);
#pragma unroll
    for (int k = 0; k < 4; ++k) d[(size_t)k * n + i] = f2b(v[k]);
  }
}

// in_w[c][ci][k] (700 contiguous per c) -> wib[c][704] bf16, pad 0
__global__ __launch_bounds__(256) void k_cvt_inw(const float* __restrict__ w,
                                                 short* __restrict__ d) {
  const int n = CH_ * KIN;
  for (int i = blockIdx.x * 256 + threadIdx.x; i < n; i += gridDim.x * 256) {
    int c = i / KIN, e = i - c * KIN;
    d[i] = (e < 700) ? f2b(w[c * 700 + e]) : (short)0;
  }
}

// dw_w [NL][512][7] fp32 -> dwt [NL][7][512] fp32
__global__ __launch_bounds__(256) void k_cvt_dwt(const float* __restrict__ w,
                                                 float* __restrict__ d) {
  const int n = NL_ * 7 * CH_;
  for (int i = blockIdx.x * 256 + threadIdx.x; i < n; i += gridDim.x * 256) {
    int l = i / (7 * CH_), r = i - l * 7 * CH_;
    int k = r >> 9, c = r & 511;
    d[i] = w[((size_t)l * CH_ + c) * 7 + k];
  }
}

// x[b][ci][t] fp32 -> xim[b*T+t][ci*7+k] = x[b,ci,t+k-3] bf16 (0 pad)
__global__ __launch_bounds__(256) void k_im2col(const float* __restrict__ x,
                                                short* __restrict__ xim) {
  const int total = BT * KIN;
  for (int i = blockIdx.x * 256 + threadIdx.x; i < total; i += gridDim.x * 256) {
    int m = i / KIN, e = i - m * KIN;
    int b = m >> 10, t = m & 1023;
    int ci = e / 7, k = e - ci * 7;
    int tt = t + k - 3;
    float v = (e < 700 && tt >= 0 && tt < T_) ? x[((b * CIN + ci) << 10) + tt] : 0.f;
    xim[i] = f2b(v);
  }
}

// zero the 4+4 pad rows of o1p per batch
__global__ __launch_bounds__(256) void k_zeropad(short* __restrict__ o1p) {
  int i = blockIdx.x * 256 + threadIdx.x;  // 131072
  int b = i >> 13;
  int r8 = (i >> 10) & 7;
  int nn = i & 1023;
  int row = r8 < 4 ? r8 : (OROWS - 8 + r8);
  o1p[((size_t)b * OROWS + row) * NFFT_ + nn] = 0;
}

// ---------------- layernorm bf16 -> bf16 (row of 512) -----------------------
__global__ __launch_bounds__(256) void k_lnb(const short* __restrict__ in,
                                             short* __restrict__ outp,
                                             const float* __restrict__ g,
                                             const float* __restrict__ bta) {
  int row = blockIdx.x, tid = threadIdx.x;
  unsigned u = *reinterpret_cast<const unsigned*>(&in[(size_t)row * CH_ + tid * 2]);
  float v0 = __uint_as_float(u << 16);
  float v1 = __uint_as_float(u & 0xffff0000u);
  float s = v0 + v1, q = v0 * v0 + v1 * v1;
#pragma unroll
  for (int o = 32; o > 0; o >>= 1) { s += __shfl_down(s, o); q += __shfl_down(q, o); }
  __shared__ float sh[8];
  int wid = tid >> 6, lane = tid & 63;
  if (lane == 0) { sh[wid] = s; sh[wid + 4] = q; }
  __syncthreads();
  float S = sh[0] + sh[1] + sh[2] + sh[3];
  float Q = sh[4] + sh[5] + sh[6] + sh[7];
  float mu  = S * (1.f / 512.f);
  float var = Q * (1.f / 512.f) - mu * mu;
  float r = rsqrtf(var + 1e-5f);
  float x0 = (v0 - mu) * r * g[tid * 2]     + bta[tid * 2];
  float x1 = (v1 - mu) * r * g[tid * 2 + 1] + bta[tid * 2 + 1];
  unsigned o = ((unsigned)(unsigned short)f2b(x0)) |
               (((unsigned)(unsigned short)f2b(x1)) << 16);
  *reinterpret_cast<unsigned*>(&outp[(size_t)row * CH_ + tid * 2]) = o;
}

// ---------------- fused depthwise 7-tap + LN, bf16, wave-per-row ------------
__global__ __launch_bounds__(256) void k_dwln(const short* __restrict__ h,
                                              const float* __restrict__ dwt,  // [7][512]
                                              const float* __restrict__ dwb,
                                              const float* __restrict__ g,
                                              const float* __restrict__ bta,
                                              short* __restrict__ yb) {
  int b = blockIdx.x, t0 = blockIdx.y * 32;
  int tid = threadIdx.x, lane = tid & 63, w = tid >> 6;
  __shared__ short hs[38][512];
  for (int e = tid; e < 38 * 64; e += 256) {
    int row = e >> 6, seg = (e & 63) << 3;
    int t = t0 - 3 + row;
    s16x8 v = {};
    if (t >= 0 && t < T_)
      v = *reinterpret_cast<const s16x8*>(&h[((size_t)((b << 10) + t)) * CH_ + seg]);
    *reinterpret_cast<s16x8*>(&hs[row][seg]) = v;
  }
  const int c0 = lane << 3;
  float wk[7][8];
#pragma unroll
  for (int k = 0; k < 7; ++k) {
    f32x4 lo = *reinterpret_cast<const f32x4*>(&dwt[k * CH_ + c0]);
    f32x4 hi = *reinterpret_cast<const f32x4*>(&dwt[k * CH_ + c0 + 4]);
#pragma unroll
    for (int j = 0; j < 4; ++j) { wk[k][j] = lo[j]; wk[k][j + 4] = hi[j]; }
  }
  float bb[8], gg[8], be[8];
  {
    f32x4 a = *reinterpret_cast<const f32x4*>(&dwb[c0]);
    f32x4 b4 = *reinterpret_cast<const f32x4*>(&dwb[c0 + 4]);
    f32x4 c = *reinterpret_cast<const f32x4*>(&g[c0]);
    f32x4 d = *reinterpret_cast<const f32x4*>(&g[c0 + 4]);
    f32x4 e = *reinterpret_cast<const f32x4*>(&bta[c0]);
    f32x4 f = *reinterpret_cast<const f32x4*>(&bta[c0 + 4]);
#pragma unroll
    for (int j = 0; j < 4; ++j) {
      bb[j] = a[j]; bb[j + 4] = b4[j];
      gg[j] = c[j]; gg[j + 4] = d[j];
      be[j] = e[j]; be[j + 4] = f[j];
    }
  }
  __syncthreads();
#pragma unroll
  for (int i = 0; i < 8; ++i) {
    int r = w * 8 + i;
    float acc[8];
#pragma unroll
    for (int j = 0; j < 8; ++j) acc[j] = bb[j];
#pragma unroll
    for (int k = 0; k < 7; ++k) {
      s16x8 hv = *reinterpret_cast<const s16x8*>(&hs[r + k][c0]);
#pragma unroll
      for (int j = 0; j < 8; ++j) acc[j] += b2f(hv[j]) * wk[k][j];
    }
    float s = 0.f, q = 0.f;
#pragma unroll
    for (int j = 0; j < 8; ++j) { s += acc[j]; q += acc[j] * acc[j]; }
#pragma unroll
    for (int o = 32; o > 0; o >>= 1) { s += __shfl_xor(s, o); q += __shfl_xor(q, o); }
    float mu  = s * (1.f / 512.f);
    float var = q * (1.f / 512.f) - mu * mu;
    float rr = rsqrtf(var + 1e-5f);
    s16x8 ov;
#pragma unroll
    for (int j = 0; j < 8; ++j) ov[j] = f2b((acc[j] - mu) * rr * gg[j] + be[j]);
    *reinterpret_cast<s16x8*>(&yb[((size_t)((b << 10) + t0 + r)) * CH_ + c0]) = ov;
  }
}

// ---------------- bf16 MFMA GEMM: C[m,n] = sum_k A[m,k]*Bw[n,k] -------------
// 128x128 tile, 4 waves, TRUE 2-deep pipeline with counted vmcnt (T3+T4):
// prologue stages tiles 0,1; per step: wait vmcnt(loads-of-next-tile) so only
// the CURRENT buffer's loads are drained (next tile's stay in flight across
// the barrier), raw s_barrier, compute, fence+s_barrier, stage(t+2) into the
// just-freed buffer. vmcnt never 0 in steady state.
// BK=32 -> 32KB LDS (~5 blocks/CU); swizzle (row>>1)&3. BK=64 -> 64KB LDS;
// swizzle row&7. [rule #21: same involution on source and read]
// MODE 0: obf = bf16(acc+bias)
// MODE 1: obf = bf16(gelu(acc+bias))
// MODE 2: obf[m][n] = bf16(obf + bf16((acc+bias)*scale))   (residual RMW)
// MODE 3: obf = bf16(acc+bias) at padded o1 rows (b*OROWS+4+t), stride NFFT
template <int MODE, int BK>
__global__ __launch_bounds__(256) void k_mgemm(const short* __restrict__ A,
                                               const short* __restrict__ Bw,
                                               const float* __restrict__ bias,
                                               const float* __restrict__ scale,
                                               short* __restrict__ obf,
                                               int N, int K) {
  constexpr int CPR  = BK / 8;            // 16B chunks per row
  constexpr int NCH  = BK / 16;           // staging chunks per thread (A or B)
  constexpr int TILE = 128 * BK;          // shorts per A (or B) buf
  constexpr int SSH  = (BK == 32) ? 1 : 0;  // swizzle row shift
  constexpr int SMEM = (4 * TILE > 16384) ? 4 * TILE : 16384;
  __shared__ __align__(16) short smem[SMEM];
  const int tid = threadIdx.x;
  const int lane = tid & 63, w = tid >> 6;
  const int id = blockIdx.x;
  const int ny = N >> 7;
  const int g8 = id >> 3;
  const int gq = g8 / ny;
  const int mt = (id & 7) + (gq << 3);
  const int nt_ = g8 - gq * ny;
  const int m0 = mt << 7, n0 = nt_ << 7;
  const int wr = (w >> 1) * 64, wc = (w & 1) * 64;
  f32x4 acc[4][4];
#pragma unroll
  for (int i = 0; i < 4; ++i)
#pragma unroll
    for (int j = 0; j < 4; ++j) acc[i][j] = (f32x4){0.f, 0.f, 0.f, 0.f};

  const short* Ab = A + (size_t)m0 * K;
  const short* Bb = Bw + (size_t)n0 * K;
  int r_[NCH], kk_[NCH];
#pragma unroll
  for (int j = 0; j < NCH; ++j) {
    int c = tid + j * 256;
    r_[j] = c / CPR;
    kk_[j] = (((c % CPR) ^ ((r_[j] >> SSH) & (CPR - 1))) * 8);  // inv-swizzle
  }
  const int ar = wr + (lane & 15);
  const int br = wc + (lane & 15);
  const int hi = lane >> 4;
  const int nsteps = K / BK;

  auto stage = [&](int buf, int k0) {
    short* Sa = smem + buf * 2 * TILE;
    short* Sb = Sa + TILE;
#pragma unroll
    for (int j = 0; j < NCH; ++j)
      gl2lds16(Ab + (size_t)r_[j] * K + k0 + kk_[j], Sa + (j * 256 + w * 64) * 8);
#pragma unroll
    for (int j = 0; j < NCH; ++j)
      gl2lds16(Bb + (size_t)r_[j] * K + k0 + kk_[j], Sb + (j * 256 + w * 64) * 8);
  };

  stage(0, 0);
  if (nsteps > 1) stage(1, BK);
  for (int t = 0; t < nsteps; ++t) {
    const int cur = t & 1;
    // drain ONLY the current buffer's loads; leave next tile's in flight
    if (t + 1 < nsteps) {
      if constexpr (BK == 32) asm volatile("s_waitcnt vmcnt(4)" ::: "memory");
      else                    asm volatile("s_waitcnt vmcnt(8)" ::: "memory");
    } else {
      asm volatile("s_waitcnt vmcnt(0)" ::: "memory");
    }
    __builtin_amdgcn_s_barrier();
    const short* As = smem + cur * 2 * TILE;
    const short* Bs = As + TILE;
#pragma unroll
    for (int ks = 0; ks < BK / 32; ++ks) {
      bf16x8 a[4], b[4];
#pragma unroll
      for (int f = 0; f < 4; ++f) {
        int row = ar + f * 16;
        a[f] = *reinterpret_cast<const bf16x8*>(
            &As[row * BK + (((ks * 4 + hi) ^ ((row >> SSH) & (CPR - 1))) * 8)]);
      }
#pragma unroll
      for (int f = 0; f < 4; ++f) {
        int row = br + f * 16;
        b[f] = *reinterpret_cast<const bf16x8*>(
            &Bs[row * BK + (((ks * 4 + hi) ^ ((row >> SSH) & (CPR - 1))) * 8)]);
      }
#pragma unroll
      for (int fi = 0; fi < 4; ++fi)
#pragma unroll
        for (int fj = 0; fj < 4; ++fj)
          acc[fi][fj] = __builtin_amdgcn_mfma_f32_16x16x32_bf16(a[fi], b[fj], acc[fi][fj], 0, 0, 0);
    }
    asm volatile("" ::: "memory");          // pin ds_reads above the barrier
    __builtin_amdgcn_s_barrier();           // all waves done reading buf cur
    if (t + 2 < nsteps) stage(cur, (t + 2) * BK);
  }
  // ---- epilogue: acc -> LDS (bank-conflict-free) -> coalesced 16B stores ----
  short* Cl = smem;                       // 128x128 shorts = 32KB
  const int colbase = wc + (lane & 15);
#pragma unroll
  for (int fj = 0; fj < 4; ++fj) {
    int cl = colbase + fj * 16;
    int n = n0 + cl;
    float bi = bias[n];
    float sc = (MODE == 2) ? scale[n] : 0.f;
#pragma unroll
    for (int fi = 0; fi < 4; ++fi) {
#pragma unroll
      for (int r = 0; r < 4; ++r) {
        int rl = wr + (hi << 2) + fi * 16 + r;
        float v = acc[fi][fj][r] + bi;
        if (MODE == 1) v = fast_gelu(v);
        if (MODE == 2) v *= sc;
        Cl[rl * 128 + (cl ^ (((rl >> 2) & 3) << 4))] = f2b(v);
      }
    }
  }
  __syncthreads();
  const int cs = (lane & 15) * 8;
#pragma unroll
  for (int it = 0; it < 8; ++it) {
    int rl = w * 32 + it * 4 + (lane >> 4);
    s16x8 v = *reinterpret_cast<const s16x8*>(&Cl[rl * 128 + (cs ^ (((rl >> 2) & 3) << 4))]);
    int m = m0 + rl;
    if (MODE == 2) {
      size_t idx = (size_t)m * N + n0 + cs;
      s16x8 hv = *reinterpret_cast<const s16x8*>(&obf[idx]);
      s16x8 o;
#pragma unroll
      for (int j = 0; j < 8; ++j) o[j] = f2b(b2f(hv[j]) + b2f(v[j]));
      *reinterpret_cast<s16x8*>(&obf[idx]) = o;
    } else if (MODE == 3) {
      int bb = m >> 10, t = m & 1023;
      *reinterpret_cast<s16x8*>(&obf[((size_t)(bb * OROWS + 4 + t)) * NFFT_ + n0 + cs]) = v;
    } else {
      *reinterpret_cast<s16x8*>(&obf[(size_t)m * N + n0 + cs]) = v;
    }
  }
}

// ---------------- overlap conv: 128(l)x64(c) tiles, A+B double-buffered -----
// o2[b][l][c] = sum_{k=0..3} sum_n o1p[b][l+1+k][n] * ovb[k][c][n]
// 1D grid 576, XCD-grouped: the 4 c-tiles of one (l,b) A-panel share id%8
// -> same XCD L2 -> A fetched once per panel.
__global__ __launch_bounds__(256) void k_ovgemm(const short* __restrict__ o1p,
                                                const short* __restrict__ ovb,
                                                float* __restrict__ o2) {
  __shared__ __align__(16) short As2[2][136 * 64];
  __shared__ __align__(16) short Bs2[2][64 * 64];
  const int tid = threadIdx.x;
  const int lane = tid & 63, w = tid >> 6;
  const int id = blockIdx.x;
  const int xcd = id & 7, rr = id >> 3;
  const int ct = rr & 3, phi = rr >> 2;       // phi in 0..17
  const int pp = xcd * 18 + phi;              // pair in 0..143
  const int l0 = (pp % 9) * 128, c0 = ct * 64, b = pp / 9;
  const int wr = (w >> 1) * 64, wc = (w & 1) * 32;
  f32x4 acc[4][2];
#pragma unroll
  for (int i = 0; i < 4; ++i)
#pragma unroll
    for (int j = 0; j < 2; ++j) acc[i][j] = (f32x4){0.f, 0.f, 0.f, 0.f};

  const short* Ab = o1p + (size_t)b * OROWS * NFFT_;
  const int ar = wr + (lane & 15);
  const int br = wc + (lane & 15);
  const int hi = lane >> 4;
  const int sl_row = lane >> 3;
  const int sl_j   = lane & 7;
  int br_[2], bk_[2];
#pragma unroll
  for (int j = 0; j < 2; ++j) {
    int c = tid + j * 256;
    br_[j] = c >> 3;
    bk_[j] = ((c & 7) ^ (br_[j] & 7)) * 8;
  }

  auto stageA = [&](int buf, int k0) {
    for (int cg = w; cg < 17; cg += 4) {
      int lr = cg * 8 + sl_row;
      int gr = l0 + 1 + lr;
      if (gr > OROWS - 1) gr = OROWS - 1;
      int j = sl_j ^ (lr & 7);
      gl2lds16(Ab + (size_t)gr * NFFT_ + k0 + j * 8, &As2[buf][cg * 512]);
    }
  };
  auto stageB = [&](int buf, int k0, int ksh) {
    const short* Bb = ovb + ((size_t)(ksh * HOP_ + c0)) * NFFT_;
#pragma unroll
    for (int j = 0; j < 2; ++j)
      gl2lds16(Bb + (size_t)br_[j] * NFFT_ + k0 + bk_[j],
               &Bs2[buf][(j * 256 + w * 64) * 8]);
  };

  int ab = 0, bb = 0;
  stageA(0, 0);
  stageB(0, 0, 0);
  asm volatile("s_waitcnt vmcnt(0)" ::: "memory");
  __syncthreads();
  for (int t = 0; t < 64; ++t) {            // 16 k0-steps x 4 ksh
    const int ksh = t & 3;
    const int nt = t + 1;
    if (nt < 64) {
      int nk0 = (nt >> 2) << 6;
      if ((nt & 3) == 0) stageA(ab ^ 1, nk0);
      stageB(bb ^ 1, nk0, nt & 3);
    }
    const short* As = As2[ab];
    const short* Bs = Bs2[bb];
#pragma unroll
    for (int ks = 0; ks < 2; ++ks) {
      bf16x8 a[4], bfr[2];
#pragma unroll
      for (int f = 0; f < 4; ++f) {
        int row = ar + f * 16 + ksh;
        a[f] = *reinterpret_cast<const bf16x8*>(&As[row * 64 + (((ks * 4 + hi) ^ (row & 7)) * 8)]);
      }
#pragma unroll
      for (int f = 0; f < 2; ++f) {
        int row = br + f * 16;
        bfr[f] = *reinterpret_cast<const bf16x8*>(&Bs[row * 64 + (((ks * 4 + hi) ^ (row & 7)) * 8)]);
      }
#pragma unroll
      for (int fi = 0; fi < 4; ++fi)
#pragma unroll
        for (int fj = 0; fj < 2; ++fj)
          acc[fi][fj] = __builtin_amdgcn_mfma_f32_16x16x32_bf16(a[fi], bfr[fj], acc[fi][fj], 0, 0, 0);
    }
    asm volatile("s_waitcnt vmcnt(0)" ::: "memory");
    __syncthreads();
    bb ^= 1;
    if (ksh == 3) ab ^= 1;
  }
  const int lb = l0 + wr + (hi << 2);
  const int cb = c0 + wc + (lane & 15);
#pragma unroll
  for (int fj = 0; fj < 2; ++fj) {
    int c = cb + fj * 16;
#pragma unroll
    for (int fi = 0; fi < 4; ++fi) {
#pragma unroll
      for (int r = 0; r < 4; ++r) {
        int l = lb + fi * 16 + r;
        if (l < L_) o2[((size_t)b * L_ + l) * HOP_ + c] = acc[fi][fj][r];
      }
    }
  }
}

// ---------------- final gather-sum over o2[b][l][c] -------------------------
__global__ __launch_bounds__(256) void k_oadd(const float* __restrict__ o2,
                                              float* __restrict__ out) {
  int b = blockIdx.x;
  int t = blockIdx.y * 256 + threadIdx.x;
  int m = t + 2;
  float s = 0.f;
  for (int c = 0; c < HOP_; ++c) {
    s += o2[((size_t)b * L_ + m) * HOP_ + c];
    m -= 4;
    if (m < 0) m += L_;
  }
  out[b * T_ + t] = s;
}

extern "C" void kernel_launch(void* const* d_in, const int* in_sizes, int n_in,
                              void* d_out, int out_size, void* d_ws, size_t ws_size,
                              hipStream_t stream) {
  const float* x      = (const float*)d_in[0];
  const float* in_w   = (const float*)d_in[1];
  const float* in_b   = (const float*)d_in[2];
  const float* norm_g = (const float*)d_in[3];
  const float* norm_b = (const float*)d_in[4];
  const float* dw_w   = (const float*)d_in[5];
  const float* dw_b   = (const float*)d_in[6];
  const float* ln_g   = (const float*)d_in[7];
  const float* ln_b   = (const float*)d_in[8];
  const float* pw1_w  = (const float*)d_in[9];
  const float* pw1_b  = (const float*)d_in[10];
  const float* pw2_w  = (const float*)d_in[11];
  const float* pw2_b  = (const float*)d_in[12];
  const float* ls     = (const float*)d_in[13];
  const float* normLg = (const float*)d_in[14];
  const float* normLb = (const float*)d_in[15];
  const float* out_w  = (const float*)d_in[16];
  const float* out_b  = (const float*)d_in[17];
  const float* ov_w   = (const float*)d_in[18];
  float* out = (float*)d_out;

  char* p = (char*)d_ws;
  short* hb   = (short*)p; p += (size_t)BT * CH_ * 2;        // 16.78 MB
  short* yb   = (short*)p; p += (size_t)BT * CH_ * 2;        // 16.78 MB
  short* zb   = (short*)p; p += (size_t)BT * HCH_ * 2;       // 50.33 MB
  short* pw1b = (short*)p; p += (size_t)NL_ * HCH_ * CH_ * 2;
  short* pw2b = (short*)p; p += (size_t)NL_ * CH_ * HCH_ * 2;
  short* owb  = (short*)p; p += (size_t)NFFT_ * CH_ * 2;
  short* ovb  = (short*)p; p += (size_t)4 * HOP_ * NFFT_ * 2;
  float* dwt  = (float*)p; p += (size_t)NL_ * 7 * CH_ * 4;
  short* xim  = zb;                        // alias: zb not yet used
  short* wib  = zb + (size_t)BT * KIN;     // fits (23.6 MB < 50.3 MB)
  short* hbL  = yb;                        // alias: yb dead when final LN runs
  short* o1p  = zb;                        // alias: zb dead after layer loop
  float* o2   = (float*)hb;                // spans hb + start of yb; both dead

  k_cvt4<<<4096, 256, 0, stream>>>(pw1_w, pw1b, NL_ * HCH_ * CH_ / 4);
  k_cvt4<<<4096, 256, 0, stream>>>(pw2_w, pw2b, NL_ * CH_ * HCH_ / 4);
  k_cvt4<<<512, 256, 0, stream>>>(out_w, owb, NFFT_ * CH_ / 4);
  k_cvt_ov<<<1024, 256, 0, stream>>>(ov_w, ovb);
  k_cvt_inw<<<1408, 256, 0, stream>>>(in_w, wib);
  k_cvt_dwt<<<112, 256, 0, stream>>>(dw_w, dwt);
  k_im2col<<<8192, 256, 0, stream>>>(x, xim);

  k_mgemm<0, 64><<<512, 256, 0, stream>>>(xim, wib, in_b, nullptr, hb, CH_, KIN);
  k_lnb<<<BT, 256, 0, stream>>>(hb, hb, norm_g, norm_b);
  for (int l = 0; l < NL_; ++l) {
    k_dwln<<<dim3(B_, T_ / 32), 256, 0, stream>>>(
        hb, dwt + (size_t)l * 7 * CH_, dw_b + l * CH_,
        ln_g + l * CH_, ln_b + l * CH_, yb);
    k_mgemm<1, 32><<<1536, 256, 0, stream>>>(
        yb, pw1b + (size_t)l * HCH_ * CH_, pw1_b + l * HCH_, nullptr, zb,
        HCH_, CH_);
    k_mgemm<2, 64><<<512, 256, 0, stream>>>(
        zb, pw2b + (size_t)l * CH_ * HCH_, pw2_b + l * CH_, ls + l * CH_, hb,
        CH_, HCH_);
  }
  k_lnb<<<BT, 256, 0, stream>>>(hb, hbL, normLg, normLb);
  k_mgemm<3, 32><<<1024, 256, 0, stream>>>(hbL, owb, out_b, nullptr, o1p, NFFT_, CH_);
  k_zeropad<<<512, 256, 0, stream>>>(o1p);
  k_ovgemm<<<576, 256, 0, stream>>>(o1p, ovb, o2);
  k_oadd<<<dim3(B_, 4), 256, 0, stream>>>(o2, out);
}

// Round 14
// 866.543 us; speedup vs baseline: 1.2113x; 1.0009x over previous
//
#include <hip/hip_runtime.h>

#define B_    16
#define CIN   100
#define T_    1024
#define CH_   512
#define HCH_  1536
#define NL_   8
#define NFFT_ 1024
#define HOP_  256
#define BT    (B_ * T_)
#define L_    1027
#define OROWS 1032   // padded o1 rows per batch: [4 zero | 1024 data | 4 zero]
#define KIN   704    // im2col K for in-conv (100*7 -> pad 704)

typedef __bf16 bf16x8 __attribute__((ext_vector_type(8)));
typedef float f32x4 __attribute__((ext_vector_type(4)));
typedef short s16x8 __attribute__((ext_vector_type(8)));
typedef short s16x4 __attribute__((ext_vector_type(4)));

__device__ __forceinline__ short f2b(float f) {
  unsigned u = __float_as_uint(f);
  u += 0x7fffu + ((u >> 16) & 1u);
  return (short)(u >> 16);
}
__device__ __forceinline__ float b2f(short s) {
  return __uint_as_float(((unsigned)(unsigned short)s) << 16);
}

// fast tanh-GELU (odd-symmetric, overflow-safe); |err| vs exact-erf ~1.5e-3
__device__ __forceinline__ float fast_gelu(float x) {
  float ax = fabsf(x);
  float z = 0.7978845608f * ax * (1.f + 0.044715f * ax * ax);
  float e = __expf(-2.f * z);
  float th = 1.f - 2.f * e * __builtin_amdgcn_rcpf(1.f + e);  // tanh(z) >= 0
  float g = copysignf(th, x);
  return 0.5f * x * (1.f + g);
}

__device__ __forceinline__ void gl2lds16(const void* g, void* l) {
  __builtin_amdgcn_global_load_lds(
      (__attribute__((address_space(1))) void*)g,
      (__attribute__((address_space(3))) void*)l, 16, 0, 0);
}

// ---------------- weight fp32 -> bf16, vectorized (n % 4 == 0) --------------
__global__ __launch_bounds__(256) void k_cvt4(const float* __restrict__ s,
                                              short* __restrict__ d, int n4) {
  for (int i = blockIdx.x * 256 + threadIdx.x; i < n4; i += gridDim.x * 256) {
    f32x4 v = *reinterpret_cast<const f32x4*>(&s[i * 4]);
    s16x4 o = {f2b(v[0]), f2b(v[1]), f2b(v[2]), f2b(v[3])};
    *reinterpret_cast<s16x4*>(&d[i * 4]) = o;
  }
}

// ov_w[c][n][k] -> ovb[k][c][n] bf16 (coalesced read 16B, 4 coalesced planes)
__global__ __launch_bounds__(256) void k_cvt_ov(const float* __restrict__ w,
                                                short* __restrict__ d) {
  const int n = HOP_ * NFFT_;   // (c,n) pairs
  for (int i = blockIdx.x * 256 + threadIdx.x; i < n; i += gridDim.x * 256) {
    f32x4 v = *reinterpret_cast<const f32x4*>(&w[(size_t)i * 4]);
#pragma unroll
    for (int k = 0; k < 4; ++k) d[(size_t)k * n + i] = f2b(v[k]);
  }
}

// in_w[c][ci][k] (700 contiguous per c) -> wib[c][704] bf16, pad 0
__global__ __launch_bounds__(256) void k_cvt_inw(const float* __restrict__ w,
                                                 short* __restrict__ d) {
  const int n = CH_ * KIN;
  for (int i = blockIdx.x * 256 + threadIdx.x; i < n; i += gridDim.x * 256) {
    int c = i / KIN, e = i - c * KIN;
    d[i] = (e < 700) ? f2b(w[c * 700 + e]) : (short)0;
  }
}

// dw_w [NL][512][7] fp32 -> dwt [NL][7][512] fp32
__global__ __launch_bounds__(256) void k_cvt_dwt(const float* __restrict__ w,
                                                 float* __restrict__ d) {
  const int n = NL_ * 7 * CH_;
  for (int i = blockIdx.x * 256 + threadIdx.x; i < n; i += gridDim.x * 256) {
    int l = i / (7 * CH_), r = i - l * 7 * CH_;
    int k = r >> 9, c = r & 511;
    d[i] = w[((size_t)l * CH_ + c) * 7 + k];
  }
}

// x[b][ci][t] fp32 -> xim[b*T+t][ci*7+k] = x[b,ci,t+k-3] bf16 (0 pad)
__global__ __launch_bounds__(256) void k_im2col(const float* __restrict__ x,
                                                short* __restrict__ xim) {
  const int total = BT * KIN;
  for (int i = blockIdx.x * 256 + threadIdx.x; i < total; i += gridDim.x * 256) {
    int m = i / KIN, e = i - m * KIN;
    int b = m >> 10, t = m & 1023;
    int ci = e / 7, k = e - ci * 7;
    int tt = t + k - 3;
    float v = (e < 700 && tt >= 0 && tt < T_) ? x[((b * CIN + ci) << 10) + tt] : 0.f;
    xim[i] = f2b(v);
  }
}

// zero the 4+4 pad rows of o1p per batch
__global__ __launch_bounds__(256) void k_zeropad(short* __restrict__ o1p) {
  int i = blockIdx.x * 256 + threadIdx.x;  // 131072
  int b = i >> 13;
  int r8 = (i >> 10) & 7;
  int nn = i & 1023;
  int row = r8 < 4 ? r8 : (OROWS - 8 + r8);
  o1p[((size_t)b * OROWS + row) * NFFT_ + nn] = 0;
}

// ---------------- layernorm bf16 -> bf16 (row of 512) -----------------------
__global__ __launch_bounds__(256) void k_lnb(const short* __restrict__ in,
                                             short* __restrict__ outp,
                                             const float* __restrict__ g,
                                             const float* __restrict__ bta) {
  int row = blockIdx.x, tid = threadIdx.x;
  unsigned u = *reinterpret_cast<const unsigned*>(&in[(size_t)row * CH_ + tid * 2]);
  float v0 = __uint_as_float(u << 16);
  float v1 = __uint_as_float(u & 0xffff0000u);
  float s = v0 + v1, q = v0 * v0 + v1 * v1;
#pragma unroll
  for (int o = 32; o > 0; o >>= 1) { s += __shfl_down(s, o); q += __shfl_down(q, o); }
  __shared__ float sh[8];
  int wid = tid >> 6, lane = tid & 63;
  if (lane == 0) { sh[wid] = s; sh[wid + 4] = q; }
  __syncthreads();
  float S = sh[0] + sh[1] + sh[2] + sh[3];
  float Q = sh[4] + sh[5] + sh[6] + sh[7];
  float mu  = S * (1.f / 512.f);
  float var = Q * (1.f / 512.f) - mu * mu;
  float r = rsqrtf(var + 1e-5f);
  float x0 = (v0 - mu) * r * g[tid * 2]     + bta[tid * 2];
  float x1 = (v1 - mu) * r * g[tid * 2 + 1] + bta[tid * 2 + 1];
  unsigned o = ((unsigned)(unsigned short)f2b(x0)) |
               (((unsigned)(unsigned short)f2b(x1)) << 16);
  *reinterpret_cast<unsigned*>(&outp[(size_t)row * CH_ + tid * 2]) = o;
}

// ---------------- fused depthwise 7-tap + LN, bf16, wave-per-row ------------
__global__ __launch_bounds__(256) void k_dwln(const short* __restrict__ h,
                                              const float* __restrict__ dwt,  // [7][512]
                                              const float* __restrict__ dwb,
                                              const float* __restrict__ g,
                                              const float* __restrict__ bta,
                                              short* __restrict__ yb) {
  int b = blockIdx.x, t0 = blockIdx.y * 32;
  int tid = threadIdx.x, lane = tid & 63, w = tid >> 6;
  __shared__ short hs[38][512];
  for (int e = tid; e < 38 * 64; e += 256) {
    int row = e >> 6, seg = (e & 63) << 3;
    int t = t0 - 3 + row;
    s16x8 v = {};
    if (t >= 0 && t < T_)
      v = *reinterpret_cast<const s16x8*>(&h[((size_t)((b << 10) + t)) * CH_ + seg]);
    *reinterpret_cast<s16x8*>(&hs[row][seg]) = v;
  }
  const int c0 = lane << 3;
  float wk[7][8];
#pragma unroll
  for (int k = 0; k < 7; ++k) {
    f32x4 lo = *reinterpret_cast<const f32x4*>(&dwt[k * CH_ + c0]);
    f32x4 hi = *reinterpret_cast<const f32x4*>(&dwt[k * CH_ + c0 + 4]);
#pragma unroll
    for (int j = 0; j < 4; ++j) { wk[k][j] = lo[j]; wk[k][j + 4] = hi[j]; }
  }
  float bb[8], gg[8], be[8];
  {
    f32x4 a = *reinterpret_cast<const f32x4*>(&dwb[c0]);
    f32x4 b4 = *reinterpret_cast<const f32x4*>(&dwb[c0 + 4]);
    f32x4 c = *reinterpret_cast<const f32x4*>(&g[c0]);
    f32x4 d = *reinterpret_cast<const f32x4*>(&g[c0 + 4]);
    f32x4 e = *reinterpret_cast<const f32x4*>(&bta[c0]);
    f32x4 f = *reinterpret_cast<const f32x4*>(&bta[c0 + 4]);
#pragma unroll
    for (int j = 0; j < 4; ++j) {
      bb[j] = a[j]; bb[j + 4] = b4[j];
      gg[j] = c[j]; gg[j + 4] = d[j];
      be[j] = e[j]; be[j + 4] = f[j];
    }
  }
  __syncthreads();
#pragma unroll
  for (int i = 0; i < 8; ++i) {
    int r = w * 8 + i;
    float acc[8];
#pragma unroll
    for (int j = 0; j < 8; ++j) acc[j] = bb[j];
#pragma unroll
    for (int k = 0; k < 7; ++k) {
      s16x8 hv = *reinterpret_cast<const s16x8*>(&hs[r + k][c0]);
#pragma unroll
      for (int j = 0; j < 8; ++j) acc[j] += b2f(hv[j]) * wk[k][j];
    }
    float s = 0.f, q = 0.f;
#pragma unroll
    for (int j = 0; j < 8; ++j) { s += acc[j]; q += acc[j] * acc[j]; }
#pragma unroll
    for (int o = 32; o > 0; o >>= 1) { s += __shfl_xor(s, o); q += __shfl_xor(q, o); }
    float mu  = s * (1.f / 512.f);
    float var = q * (1.f / 512.f) - mu * mu;
    float rr = rsqrtf(var + 1e-5f);
    s16x8 ov;
#pragma unroll
    for (int j = 0; j < 8; ++j) ov[j] = f2b((acc[j] - mu) * rr * gg[j] + be[j]);
    *reinterpret_cast<s16x8*>(&yb[((size_t)((b << 10) + t0 + r)) * CH_ + c0]) = ov;
  }
}

// ---------------- bf16 MFMA GEMM: C[m,n] = sum_k A[m,k]*Bw[n,k] -------------
// 128x128 tile, 4 waves, TRUE 2-deep pipeline with counted vmcnt (T3+T4).
// BK=32 -> 32KB LDS (~5 blocks/CU); swizzle (row>>1)&3. BK=64 -> 64KB LDS;
// swizzle row&7. [rule #21: same involution on source and read]
// MODE 0: obf = bf16(acc+bias)
// MODE 1: obf = bf16(gelu(acc+bias))
// MODE 2: obf[m][n] = bf16(obf + bf16((acc+bias)*scale))   (residual RMW)
// MODE 3: obf = bf16(acc+bias) at padded o1 rows (b*OROWS+4+t), stride NFFT
template <int MODE, int BK>
__global__ __launch_bounds__(256) void k_mgemm(const short* __restrict__ A,
                                               const short* __restrict__ Bw,
                                               const float* __restrict__ bias,
                                               const float* __restrict__ scale,
                                               short* __restrict__ obf,
                                               int N, int K) {
  constexpr int CPR  = BK / 8;            // 16B chunks per row
  constexpr int NCH  = BK / 16;           // staging chunks per thread (A or B)
  constexpr int TILE = 128 * BK;          // shorts per A (or B) buf
  constexpr int SSH  = (BK == 32) ? 1 : 0;  // swizzle row shift
  constexpr int SMEM = (4 * TILE > 16384) ? 4 * TILE : 16384;
  __shared__ __align__(16) short smem[SMEM];
  const int tid = threadIdx.x;
  const int lane = tid & 63, w = tid >> 6;
  const int id = blockIdx.x;
  const int ny = N >> 7;
  const int g8 = id >> 3;
  const int gq = g8 / ny;
  const int mt = (id & 7) + (gq << 3);
  const int nt_ = g8 - gq * ny;
  const int m0 = mt << 7, n0 = nt_ << 7;
  const int wr = (w >> 1) * 64, wc = (w & 1) * 64;
  f32x4 acc[4][4];
#pragma unroll
  for (int i = 0; i < 4; ++i)
#pragma unroll
    for (int j = 0; j < 4; ++j) acc[i][j] = (f32x4){0.f, 0.f, 0.f, 0.f};

  const short* Ab = A + (size_t)m0 * K;
  const short* Bb = Bw + (size_t)n0 * K;
  int r_[NCH], kk_[NCH];
#pragma unroll
  for (int j = 0; j < NCH; ++j) {
    int c = tid + j * 256;
    r_[j] = c / CPR;
    kk_[j] = (((c % CPR) ^ ((r_[j] >> SSH) & (CPR - 1))) * 8);  // inv-swizzle
  }
  const int ar = wr + (lane & 15);
  const int br = wc + (lane & 15);
  const int hi = lane >> 4;
  const int nsteps = K / BK;

  auto stage = [&](int buf, int k0) {
    short* Sa = smem + buf * 2 * TILE;
    short* Sb = Sa + TILE;
#pragma unroll
    for (int j = 0; j < NCH; ++j)
      gl2lds16(Ab + (size_t)r_[j] * K + k0 + kk_[j], Sa + (j * 256 + w * 64) * 8);
#pragma unroll
    for (int j = 0; j < NCH; ++j)
      gl2lds16(Bb + (size_t)r_[j] * K + k0 + kk_[j], Sb + (j * 256 + w * 64) * 8);
  };

  stage(0, 0);
  if (nsteps > 1) stage(1, BK);
  for (int t = 0; t < nsteps; ++t) {
    const int cur = t & 1;
    // drain ONLY the current buffer's loads; leave next tile's in flight
    if (t + 1 < nsteps) {
      if constexpr (BK == 32) asm volatile("s_waitcnt vmcnt(4)" ::: "memory");
      else                    asm volatile("s_waitcnt vmcnt(8)" ::: "memory");
    } else {
      asm volatile("s_waitcnt vmcnt(0)" ::: "memory");
    }
    __builtin_amdgcn_s_barrier();
    const short* As = smem + cur * 2 * TILE;
    const short* Bs = As + TILE;
#pragma unroll
    for (int ks = 0; ks < BK / 32; ++ks) {
      bf16x8 a[4], b[4];
#pragma unroll
      for (int f = 0; f < 4; ++f) {
        int row = ar + f * 16;
        a[f] = *reinterpret_cast<const bf16x8*>(
            &As[row * BK + (((ks * 4 + hi) ^ ((row >> SSH) & (CPR - 1))) * 8)]);
      }
#pragma unroll
      for (int f = 0; f < 4; ++f) {
        int row = br + f * 16;
        b[f] = *reinterpret_cast<const bf16x8*>(
            &Bs[row * BK + (((ks * 4 + hi) ^ ((row >> SSH) & (CPR - 1))) * 8)]);
      }
#pragma unroll
      for (int fi = 0; fi < 4; ++fi)
#pragma unroll
        for (int fj = 0; fj < 4; ++fj)
          acc[fi][fj] = __builtin_amdgcn_mfma_f32_16x16x32_bf16(a[fi], b[fj], acc[fi][fj], 0, 0, 0);
    }
    asm volatile("" ::: "memory");          // pin ds_reads above the barrier
    __builtin_amdgcn_s_barrier();           // all waves done reading buf cur
    if (t + 2 < nsteps) stage(cur, (t + 2) * BK);
  }
  // ---- epilogue: acc -> LDS (bank-conflict-free) -> coalesced 16B stores ----
  short* Cl = smem;                       // 128x128 shorts = 32KB
  const int colbase = wc + (lane & 15);
#pragma unroll
  for (int fj = 0; fj < 4; ++fj) {
    int cl = colbase + fj * 16;
    int n = n0 + cl;
    float bi = bias[n];
    float sc = (MODE == 2) ? scale[n] : 0.f;
#pragma unroll
    for (int fi = 0; fi < 4; ++fi) {
#pragma unroll
      for (int r = 0; r < 4; ++r) {
        int rl = wr + (hi << 2) + fi * 16 + r;
        float v = acc[fi][fj][r] + bi;
        if (MODE == 1) v = fast_gelu(v);
        if (MODE == 2) v *= sc;
        Cl[rl * 128 + (cl ^ (((rl >> 2) & 3) << 4))] = f2b(v);
      }
    }
  }
  __syncthreads();
  const int cs = (lane & 15) * 8;
#pragma unroll
  for (int it = 0; it < 8; ++it) {
    int rl = w * 32 + it * 4 + (lane >> 4);
    s16x8 v = *reinterpret_cast<const s16x8*>(&Cl[rl * 128 + (cs ^ (((rl >> 2) & 3) << 4))]);
    int m = m0 + rl;
    if (MODE == 2) {
      size_t idx = (size_t)m * N + n0 + cs;
      s16x8 hv = *reinterpret_cast<const s16x8*>(&obf[idx]);
      s16x8 o;
#pragma unroll
      for (int j = 0; j < 8; ++j) o[j] = f2b(b2f(hv[j]) + b2f(v[j]));
      *reinterpret_cast<s16x8*>(&obf[idx]) = o;
    } else if (MODE == 3) {
      int bb = m >> 10, t = m & 1023;
      *reinterpret_cast<s16x8*>(&obf[((size_t)(bb * OROWS + 4 + t)) * NFFT_ + n0 + cs]) = v;
    } else {
      *reinterpret_cast<s16x8*>(&obf[(size_t)m * N + n0 + cs]) = v;
    }
  }
}

// ---------------- overlap conv: counted-vmcnt 2-deep pipeline ---------------
// o2[b][l][c] = sum_{k=0..3} sum_n o1p[b][l+1+k][n] * ovb[k][c][n]
// 64 phases (16 k0 x 4 ksh). B dbuf restaged each phase for t+2 (2 loads/thr);
// A dbuf restaged at ksh==3 for k0-block t/4+2 (wave0:5, w1-3:4 loads).
// FIFO-derived wait table: t%4<2 && t<58 -> vmcnt(7/6) (keep A+nextB);
// t==63 -> vmcnt(0); else vmcnt(2) (keep next B only).
__global__ __launch_bounds__(256) void k_ovgemm(const short* __restrict__ o1p,
                                                const short* __restrict__ ovb,
                                                float* __restrict__ o2) {
  __shared__ __align__(16) short As2[2][136 * 64];
  __shared__ __align__(16) short Bs2[2][64 * 64];
  const int tid = threadIdx.x;
  const int lane = tid & 63, w = tid >> 6;
  const int id = blockIdx.x;
  const int xcd = id & 7, rrr = id >> 3;
  const int ct = rrr & 3, phi = rrr >> 2;     // phi in 0..17
  const int pp = xcd * 18 + phi;              // pair in 0..143
  const int l0 = (pp % 9) * 128, c0 = ct * 64, b = pp / 9;
  const int wr = (w >> 1) * 64, wc = (w & 1) * 32;
  f32x4 acc[4][2];
#pragma unroll
  for (int i = 0; i < 4; ++i)
#pragma unroll
    for (int j = 0; j < 2; ++j) acc[i][j] = (f32x4){0.f, 0.f, 0.f, 0.f};

  const short* Ab = o1p + (size_t)b * OROWS * NFFT_;
  const int ar = wr + (lane & 15);
  const int br = wc + (lane & 15);
  const int hi = lane >> 4;
  const int sl_row = lane >> 3;
  const int sl_j   = lane & 7;
  int br_[2], bk_[2];
#pragma unroll
  for (int j = 0; j < 2; ++j) {
    int c = tid + j * 256;
    br_[j] = c >> 3;
    bk_[j] = ((c & 7) ^ (br_[j] & 7)) * 8;
  }

  auto stageA = [&](int buf, int k0) {
    for (int cg = w; cg < 17; cg += 4) {      // wave0: 5 chunks, w1-3: 4
      int lr = cg * 8 + sl_row;
      int gr = l0 + 1 + lr;
      if (gr > OROWS - 1) gr = OROWS - 1;     // clamp into zero pad
      int j = sl_j ^ (lr & 7);
      gl2lds16(Ab + (size_t)gr * NFFT_ + k0 + j * 8, &As2[buf][cg * 512]);
    }
  };
  auto stageB = [&](int buf, int k0, int ksh) {
    const short* Bb = ovb + ((size_t)(ksh * HOP_ + c0)) * NFFT_;
#pragma unroll
    for (int j = 0; j < 2; ++j)
      gl2lds16(Bb + (size_t)br_[j] * NFFT_ + k0 + bk_[j],
               &Bs2[buf][(j * 256 + w * 64) * 8]);
  };

  // prologue (FIFO order matters: A0, B0, B1, A1)
  stageA(0, 0);
  stageB(0, 0, 0);
  stageB(1, 0, 1);
  stageA(1, 64);

  for (int t = 0; t < 64; ++t) {
    const int ab = (t >> 2) & 1;
    const int bbuf = t & 1;
    const int ksh = t & 3;
    if (t == 63) {
      asm volatile("s_waitcnt vmcnt(0)" ::: "memory");
    } else if ((t & 3) < 2 && t < 58) {       // A (4/5) + next-B (2) in flight
      if (w == 0) asm volatile("s_waitcnt vmcnt(7)" ::: "memory");
      else        asm volatile("s_waitcnt vmcnt(6)" ::: "memory");
    } else {
      asm volatile("s_waitcnt vmcnt(2)" ::: "memory");
    }
    __builtin_amdgcn_s_barrier();
    const short* As = As2[ab];
    const short* Bs = Bs2[bbuf];
#pragma unroll
    for (int ks = 0; ks < 2; ++ks) {
      bf16x8 a[4], bfr[2];
#pragma unroll
      for (int f = 0; f < 4; ++f) {
        int row = ar + f * 16 + ksh;          // shifted A row
        a[f] = *reinterpret_cast<const bf16x8*>(&As[row * 64 + (((ks * 4 + hi) ^ (row & 7)) * 8)]);
      }
#pragma unroll
      for (int f = 0; f < 2; ++f) {
        int row = br + f * 16;
        bfr[f] = *reinterpret_cast<const bf16x8*>(&Bs[row * 64 + (((ks * 4 + hi) ^ (row & 7)) * 8)]);
      }
#pragma unroll
      for (int fi = 0; fi < 4; ++fi)
#pragma unroll
        for (int fj = 0; fj < 2; ++fj)
          acc[fi][fj] = __builtin_amdgcn_mfma_f32_16x16x32_bf16(a[fi], bfr[fj], acc[fi][fj], 0, 0, 0);
    }
    // my ds_reads complete before signaling others may overwrite these bufs
    asm volatile("s_waitcnt lgkmcnt(0)" ::: "memory");
    __builtin_amdgcn_sched_barrier(0);
    __builtin_amdgcn_s_barrier();
    if (t + 2 < 64) {                         // restage B (buf just read) for t+2
      int nt = t + 2;
      stageB(bbuf, (nt >> 2) << 6, nt & 3);
    }
    if (ksh == 3) {                           // restage A (buf just freed)
      int nb = (t >> 2) + 2;
      if (nb < 16) stageA(ab, nb << 6);
    }
  }
  const int lb = l0 + wr + (hi << 2);
  const int cb = c0 + wc + (lane & 15);
#pragma unroll
  for (int fj = 0; fj < 2; ++fj) {
    int c = cb + fj * 16;
#pragma unroll
    for (int fi = 0; fi < 4; ++fi) {
#pragma unroll
      for (int r = 0; r < 4; ++r) {
        int l = lb + fi * 16 + r;
        if (l < L_) o2[((size_t)b * L_ + l) * HOP_ + c] = acc[fi][fj][r];
      }
    }
  }
}

// ---------------- final gather-sum over o2[b][l][c] -------------------------
__global__ __launch_bounds__(256) void k_oadd(const float* __restrict__ o2,
                                              float* __restrict__ out) {
  int b = blockIdx.x;
  int t = blockIdx.y * 256 + threadIdx.x;
  int m = t + 2;
  float s = 0.f;
  for (int c = 0; c < HOP_; ++c) {
    s += o2[((size_t)b * L_ + m) * HOP_ + c];
    m -= 4;
    if (m < 0) m += L_;
  }
  out[b * T_ + t] = s;
}

extern "C" void kernel_launch(void* const* d_in, const int* in_sizes, int n_in,
                              void* d_out, int out_size, void* d_ws, size_t ws_size,
                              hipStream_t stream) {
  const float* x      = (const float*)d_in[0];
  const float* in_w   = (const float*)d_in[1];
  const float* in_b   = (const float*)d_in[2];
  const float* norm_g = (const float*)d_in[3];
  const float* norm_b = (const float*)d_in[4];
  const float* dw_w   = (const float*)d_in[5];
  const float* dw_b   = (const float*)d_in[6];
  const float* ln_g   = (const float*)d_in[7];
  const float* ln_b   = (const float*)d_in[8];
  const float* pw1_w  = (const float*)d_in[9];
  const float* pw1_b  = (const float*)d_in[10];
  const float* pw2_w  = (const float*)d_in[11];
  const float* pw2_b  = (const float*)d_in[12];
  const float* ls     = (const float*)d_in[13];
  const float* normLg = (const float*)d_in[14];
  const float* normLb = (const float*)d_in[15];
  const float* out_w  = (const float*)d_in[16];
  const float* out_b  = (const float*)d_in[17];
  const float* ov_w   = (const float*)d_in[18];
  float* out = (float*)d_out;

  char* p = (char*)d_ws;
  short* hb   = (short*)p; p += (size_t)BT * CH_ * 2;        // 16.78 MB
  short* yb   = (short*)p; p += (size_t)BT * CH_ * 2;        // 16.78 MB
  short* zb   = (short*)p; p += (size_t)BT * HCH_ * 2;       // 50.33 MB
  short* pw1b = (short*)p; p += (size_t)NL_ * HCH_ * CH_ * 2;
  short* pw2b = (short*)p; p += (size_t)NL_ * CH_ * HCH_ * 2;
  short* owb  = (short*)p; p += (size_t)NFFT_ * CH_ * 2;
  short* ovb  = (short*)p; p += (size_t)4 * HOP_ * NFFT_ * 2;
  float* dwt  = (float*)p; p += (size_t)NL_ * 7 * CH_ * 4;
  short* xim  = zb;                        // alias: zb not yet used
  short* wib  = zb + (size_t)BT * KIN;     // fits (23.6 MB < 50.3 MB)
  short* hbL  = yb;                        // alias: yb dead when final LN runs
  short* o1p  = zb;                        // alias: zb dead after layer loop
  float* o2   = (float*)hb;                // spans hb + start of yb; both dead

  k_cvt4<<<4096, 256, 0, stream>>>(pw1_w, pw1b, NL_ * HCH_ * CH_ / 4);
  k_cvt4<<<4096, 256, 0, stream>>>(pw2_w, pw2b, NL_ * CH_ * HCH_ / 4);
  k_cvt4<<<512, 256, 0, stream>>>(out_w, owb, NFFT_ * CH_ / 4);
  k_cvt_ov<<<1024, 256, 0, stream>>>(ov_w, ovb);
  k_cvt_inw<<<1408, 256, 0, stream>>>(in_w, wib);
  k_cvt_dwt<<<112, 256, 0, stream>>>(dw_w, dwt);
  k_im2col<<<8192, 256, 0, stream>>>(x, xim);

  k_mgemm<0, 64><<<512, 256, 0, stream>>>(xim, wib, in_b, nullptr, hb, CH_, KIN);
  k_lnb<<<BT, 256, 0, stream>>>(hb, hb, norm_g, norm_b);
  for (int l = 0; l < NL_; ++l) {
    k_dwln<<<dim3(B_, T_ / 32), 256, 0, stream>>>(
        hb, dwt + (size_t)l * 7 * CH_, dw_b + l * CH_,
        ln_g + l * CH_, ln_b + l * CH_, yb);
    k_mgemm<1, 32><<<1536, 256, 0, stream>>>(
        yb, pw1b + (size_t)l * HCH_ * CH_, pw1_b + l * HCH_, nullptr, zb,
        HCH_, CH_);
    k_mgemm<2, 64><<<512, 256, 0, stream>>>(
        zb, pw2b + (size_t)l * CH_ * HCH_, pw2_b + l * CH_, ls + l * CH_, hb,
        CH_, HCH_);
  }
  k_lnb<<<BT, 256, 0, stream>>>(hb, hbL, normLg, normLb);
  k_mgemm<3, 32><<<1024, 256, 0, stream>>>(hbL, owb, out_b, nullptr, o1p, NFFT_, CH_);
  k_zeropad<<<512, 256, 0, stream>>>(o1p);
  k_ovgemm<<<576, 256, 0, stream>>>(o1p, ovb, o2);
  k_oadd<<<dim3(B_, 4), 256, 0, stream>>>(o2, out);
}